// Round 1
// baseline (1313.106 us; speedup 1.0000x reference)
//
#include <hip/hip_runtime.h>
#include <hip/hip_bf16.h>

#define NB 32
#define NPOS 4096
#define NSLOT 8
#define HIDD 256
#define DDIM 256
#define DMLP 512
#define SCALE_F 0.0625f
#define EPS_F 1e-8f

#define XPAD 260   // bf16 stride for LNx tile rows in LDS (520B -> 2-way max on row reads)
#define QKP 264    // bf16 stride for qk rows in LDS (528B -> conflict-free slot reads)

__device__ __forceinline__ unsigned short f2bf(float f) {
    unsigned int x = __float_as_uint(f);
    x = (x + 0x7fffu + ((x >> 16) & 1u)) >> 16;
    return (unsigned short)x;
}

// ---------------- Kernel 1: LayerNorm(inputs) -> bf16, one wave per row ----------------
__global__ __launch_bounds__(256) void k_ln_in(
        const float* __restrict__ x, const float* __restrict__ g,
        const float* __restrict__ b, unsigned short* __restrict__ lnx) {
    int lane = threadIdx.x & 63;
    int wave = threadIdx.x >> 6;
    long row = (long)blockIdx.x * 4 + wave;
    const float4* xr = (const float4*)(x + row * 256);
    float4 v = xr[lane];
    float s = v.x + v.y + v.z + v.w;
    float sq = v.x * v.x + v.y * v.y + v.z * v.z + v.w * v.w;
    #pragma unroll
    for (int m = 32; m; m >>= 1) { s += __shfl_xor(s, m); sq += __shfl_xor(sq, m); }
    float mean = s * 0.00390625f;
    float rstd = rsqrtf(sq * 0.00390625f - mean * mean + 1e-5f);
    const float4 gg = ((const float4*)g)[lane];
    const float4 bb = ((const float4*)b)[lane];
    ushort4 o;
    o.x = f2bf((v.x - mean) * rstd * gg.x + bb.x);
    o.y = f2bf((v.y - mean) * rstd * gg.y + bb.y);
    o.z = f2bf((v.z - mean) * rstd * gg.z + bb.z);
    o.w = f2bf((v.w - mean) * rstd * gg.w + bb.w);
    ((ushort4*)(lnx + row * 256))[lane] = o;
}

// ---- Kernel A (per iter): slots LN -> q -> qk = SCALE*(q @ Wk^T), qbk; zero U/denom ----
// one block per batch (8 slot rows)
__global__ __launch_bounds__(256) void k_pre(
        const float* __restrict__ noise, const float* __restrict__ mu,
        const float* __restrict__ sig, const float* __restrict__ lng,
        const float* __restrict__ lnb, const float* __restrict__ Wq,
        const float* __restrict__ bq, const float* __restrict__ Wk,
        const float* __restrict__ bk, float* __restrict__ slots,
        unsigned short* __restrict__ qk, float* __restrict__ qbk,
        float* __restrict__ U, float* __restrict__ denom, int iter) {
    __shared__ float sln[8][256];
    __shared__ float qs[8][256];
    __shared__ float red[8][8];
    int b = blockIdx.x;
    int t = threadIdx.x;
    int lane = t & 63, wave = t >> 6;
    for (int s = 0; s < 8; s++) {
        int gi = (b * 8 + s) * 256 + t;
        float xv;
        if (iter == 0) { xv = mu[t] + sig[t] * noise[gi]; slots[gi] = xv; }
        else xv = slots[gi];
        sln[s][t] = xv;
    }
    __syncthreads();
    // LN per row: wave w handles rows 2w, 2w+1
    for (int rr = 0; rr < 2; rr++) {
        int s = wave * 2 + rr;
        float ss = 0.f, sq = 0.f;
        #pragma unroll
        for (int j = 0; j < 4; j++) { float xv = sln[s][lane * 4 + j]; ss += xv; sq += xv * xv; }
        #pragma unroll
        for (int m = 32; m; m >>= 1) { ss += __shfl_xor(ss, m); sq += __shfl_xor(sq, m); }
        float mean = ss * 0.00390625f;
        float rstd = rsqrtf(sq * 0.00390625f - mean * mean + 1e-5f);
        #pragma unroll
        for (int j = 0; j < 4; j++) {
            int d = lane * 4 + j;
            sln[s][d] = (sln[s][d] - mean) * rstd * lng[d] + lnb[d];
        }
    }
    __syncthreads();
    // q[s][t] = bq[t] + sum_h sln[s][h] * Wq[h][t]
    float qa[8];
    #pragma unroll
    for (int s = 0; s < 8; s++) qa[s] = bq[t];
    for (int h = 0; h < 256; h += 4) {
        float w0 = Wq[(h+0)*256+t], w1 = Wq[(h+1)*256+t];
        float w2 = Wq[(h+2)*256+t], w3 = Wq[(h+3)*256+t];
        #pragma unroll
        for (int s = 0; s < 8; s++) {
            float4 sv = *(const float4*)&sln[s][h];
            qa[s] += sv.x*w0 + sv.y*w1 + sv.z*w2 + sv.w*w3;
        }
    }
    #pragma unroll
    for (int s = 0; s < 8; s++) qs[s][t] = qa[s];
    {   // qbk[s] = SCALE * sum_d q[s][d]*bk[d]
        float bkt = bk[t];
        #pragma unroll
        for (int s = 0; s < 8; s++) {
            float cpart = qa[s] * bkt;
            #pragma unroll
            for (int m = 32; m; m >>= 1) cpart += __shfl_xor(cpart, m);
            if (lane == 0) red[s][wave] = cpart;
        }
    }
    __syncthreads();
    if (t < 8) qbk[b * 8 + t] = SCALE_F * (red[t][0] + red[t][1] + red[t][2] + red[t][3]);
    // qk[s][t(=h)] = SCALE * sum_d q[s][d] * Wk[t*256+d]  (bf16 out)
    float ka[8] = {0.f,0.f,0.f,0.f,0.f,0.f,0.f,0.f};
    for (int d = 0; d < 256; d += 4) {
        float4 wk = *(const float4*)&Wk[t * 256 + d];
        #pragma unroll
        for (int s = 0; s < 8; s++) {
            float4 qv = *(const float4*)&qs[s][d];
            ka[s] += qv.x*wk.x + qv.y*wk.y + qv.z*wk.z + qv.w*wk.w;
        }
    }
    #pragma unroll
    for (int s = 0; s < 8; s++) qk[(b * 8 + s) * 256 + t] = f2bf(SCALE_F * ka[s]);
    #pragma unroll
    for (int s = 0; s < 8; s++) U[(b * 8 + s) * 256 + t] = 0.f;
    if (t < 8) denom[b * 8 + t] = 0.f;
}

// -------- Kernel B (per iter): streaming dots -> per-position softmax -> U, denom --------
// grid = 32 batches x 16 chunks; 256 threads; chunk = 4 tiles of 64 positions
__global__ __launch_bounds__(256) void k_stream(
        const unsigned short* __restrict__ lnx, const unsigned short* __restrict__ qk,
        const float* __restrict__ qbk, float* __restrict__ U, float* __restrict__ denom) {
    __shared__ unsigned short tileX[64 * XPAD];
    __shared__ unsigned short qkL[8 * QKP];
    __shared__ float attnL[64][8];
    __shared__ float qbkL[8];
    int b = blockIdx.x >> 4;
    int chunk = blockIdx.x & 15;
    int t = threadIdx.x;
    {
        int s = t >> 5, j = t & 31;
        int4 v = *((const int4*)(qk + (b * 8 + s) * 256) + j);
        *(int4*)&qkL[s * QKP + j * 8] = v;
        if (t < 8) qbkL[t] = qbk[b * 8 + t];
    }
    float Ureg[8] = {0.f,0.f,0.f,0.f,0.f,0.f,0.f,0.f};
    float dreg = 0.f;
    int s2 = t >> 5, c2 = t & 31;
    int p1n = t >> 2, sl0 = (t & 3) * 2;
    const int4* gbase = (const int4*)(lnx + ((long)b * NPOS + chunk * 256) * 256);
    for (int tile = 0; tile < 4; tile++) {
        __syncthreads();
        const int4* gsrc = gbase + tile * (64 * 32);
        #pragma unroll
        for (int i = 0; i < 8; i++) {
            int idx = t + 256 * i;
            int4 v = gsrc[idx];
            *(int4*)&tileX[(idx >> 5) * XPAD + (idx & 31) * 8] = v;
        }
        __syncthreads();
        // phase1: dots + per-position softmax over 8 slots (4 threads/pos, 2 slots each)
        {
            float a0 = qbkL[sl0], a1 = qbkL[sl0 + 1];
            const unsigned short* xr = &tileX[p1n * XPAD];
            const unsigned short* q0 = &qkL[sl0 * QKP];
            const unsigned short* q1 = &qkL[(sl0 + 1) * QKP];
            for (int hh = 0; hh < 256; hh += 8) {
                int4 xv = *(const int4*)&xr[hh];
                int4 v0 = *(const int4*)&q0[hh];
                int4 v1 = *(const int4*)&q1[hh];
                const unsigned int* px = (const unsigned int*)&xv;
                const unsigned int* p0 = (const unsigned int*)&v0;
                const unsigned int* p1 = (const unsigned int*)&v1;
                #pragma unroll
                for (int i = 0; i < 4; i++) {
                    float xlo = __uint_as_float(px[i] << 16);
                    float xhi = __uint_as_float(px[i] & 0xffff0000u);
                    a0 += xlo * __uint_as_float(p0[i] << 16) + xhi * __uint_as_float(p0[i] & 0xffff0000u);
                    a1 += xlo * __uint_as_float(p1[i] << 16) + xhi * __uint_as_float(p1[i] & 0xffff0000u);
                }
            }
            float mx = fmaxf(a0, a1);
            mx = fmaxf(mx, __shfl_xor(mx, 1));
            mx = fmaxf(mx, __shfl_xor(mx, 2));
            float e0 = __expf(a0 - mx), e1 = __expf(a1 - mx);
            float sm = e0 + e1;
            sm += __shfl_xor(sm, 1);
            sm += __shfl_xor(sm, 2);
            float inv = 1.0f / sm;
            attnL[p1n][sl0]     = e0 * inv;
            attnL[p1n][sl0 + 1] = e1 * inv;
        }
        __syncthreads();
        // phase2: U[s][h] += attn[n][s] * x[n][h]  (thread = (slot, 8-wide h chunk))
        {
            dreg += attnL[c2][s2] + attnL[c2 + 32][s2];
            for (int n = 0; n < 64; n++) {
                float a = attnL[n][s2];
                int4 xv = *(const int4*)&tileX[n * XPAD + c2 * 8];
                const unsigned int* px = (const unsigned int*)&xv;
                #pragma unroll
                for (int i = 0; i < 4; i++) {
                    Ureg[2*i]   += a * __uint_as_float(px[i] << 16);
                    Ureg[2*i+1] += a * __uint_as_float(px[i] & 0xffff0000u);
                }
            }
        }
    }
    #pragma unroll
    for (int j = 0; j < 8; j++)
        atomicAdd(&U[(b * 8 + s2) * 256 + c2 * 8 + j], Ureg[j]);
    atomicAdd(&denom[b * 8 + s2], dreg);
}

// ---- Kernel C (per iter): updates = U@Wv/denom + bv -> GRU -> LN -> MLP -> new slots ----
// grid = 64 blocks (half-batch = 4 rows), 512 threads: (c = col, g = row-pair)
__global__ __launch_bounds__(512) void k_post(
        const float* __restrict__ U, const float* __restrict__ denom,
        const float* __restrict__ Wv, const float* __restrict__ bv,
        const float* __restrict__ Wih, const float* __restrict__ Whh,
        const float* __restrict__ bih, const float* __restrict__ bhh,
        const float* __restrict__ lng, const float* __restrict__ lnb,
        const float* __restrict__ W1, const float* __restrict__ b1,
        const float* __restrict__ W2, const float* __restrict__ b2,
        float* __restrict__ slots, float* __restrict__ outp, int last) {
    __shared__ float Us[4][256], upd[4][256], slp[4][256], mm[4][256];
    __shared__ float hid[4][512];
    __shared__ float red[8][4];
    int r0 = blockIdx.x * 4;
    int t = threadIdx.x;
    int c = t & 255, g = t >> 8;
    #pragma unroll
    for (int i = 0; i < 2; i++) {
        int idx = t + 512 * i;
        int rr = idx >> 8, d = idx & 255;
        Us[rr][d]  = U[(r0 + rr) * 256 + d];
        slp[rr][d] = slots[(r0 + rr) * 256 + d];
    }
    __syncthreads();
    float dn0 = 1.0f / (denom[r0 + 2*g]     + (float)NPOS * EPS_F);
    float dn1 = 1.0f / (denom[r0 + 2*g + 1] + (float)NPOS * EPS_F);
    float ua0 = 0.f, ua1 = 0.f;
    for (int h = 0; h < 256; h += 4) {
        float w0 = Wv[(h+0)*256+c], w1 = Wv[(h+1)*256+c];
        float w2 = Wv[(h+2)*256+c], w3 = Wv[(h+3)*256+c];
        float4 u0 = *(const float4*)&Us[2*g][h];
        float4 u1 = *(const float4*)&Us[2*g+1][h];
        ua0 += u0.x*w0 + u0.y*w1 + u0.z*w2 + u0.w*w3;
        ua1 += u1.x*w0 + u1.y*w1 + u1.z*w2 + u1.w*w3;
    }
    upd[2*g][c]   = ua0 * dn0 + bv[c];
    upd[2*g+1][c] = ua1 * dn1 + bv[c];
    __syncthreads();
    // GRU
    float hnew0, hnew1;
    {
        float gi0[3], gi1[3], gh0[3], gh1[3];
        #pragma unroll
        for (int j = 0; j < 3; j++) {
            gi0[j] = gi1[j] = bih[c + 256*j];
            gh0[j] = gh1[j] = bhh[c + 256*j];
        }
        for (int d = 0; d < 256; d++) {
            float u0 = upd[2*g][d], u1 = upd[2*g+1][d];
            float s0 = slp[2*g][d], s1 = slp[2*g+1][d];
            #pragma unroll
            for (int j = 0; j < 3; j++) {
                float wi = Wih[d*768 + 256*j + c];
                float wh = Whh[d*768 + 256*j + c];
                gi0[j] += u0 * wi; gi1[j] += u1 * wi;
                gh0[j] += s0 * wh; gh1[j] += s1 * wh;
            }
        }
        float rg0 = 1.f/(1.f+__expf(-(gi0[0]+gh0[0])));
        float zg0 = 1.f/(1.f+__expf(-(gi0[1]+gh0[1])));
        float ng0 = tanhf(gi0[2] + rg0*gh0[2]);
        hnew0 = (1.f - zg0)*ng0 + zg0*slp[2*g][c];
        float rg1 = 1.f/(1.f+__expf(-(gi1[0]+gh1[0])));
        float zg1 = 1.f/(1.f+__expf(-(gi1[1]+gh1[1])));
        float ng1 = tanhf(gi1[2] + rg1*gh1[2]);
        hnew1 = (1.f - zg1)*ng1 + zg1*slp[2*g+1][c];
    }
    // LN(hnew) per row: rows of group g live on waves g*4..g*4+3
    {
        int wave = t >> 6;
        float s0 = hnew0, q0 = hnew0*hnew0, s1 = hnew1, q1 = hnew1*hnew1;
        #pragma unroll
        for (int m = 32; m; m >>= 1) {
            s0 += __shfl_xor(s0, m); q0 += __shfl_xor(q0, m);
            s1 += __shfl_xor(s1, m); q1 += __shfl_xor(q1, m);
        }
        if ((t & 63) == 0) { red[wave][0]=s0; red[wave][1]=q0; red[wave][2]=s1; red[wave][3]=q1; }
        __syncthreads();
        int wb = g * 4;
        float S0 = red[wb][0]+red[wb+1][0]+red[wb+2][0]+red[wb+3][0];
        float Q0 = red[wb][1]+red[wb+1][1]+red[wb+2][1]+red[wb+3][1];
        float S1 = red[wb][2]+red[wb+1][2]+red[wb+2][2]+red[wb+3][2];
        float Q1 = red[wb][3]+red[wb+1][3]+red[wb+2][3]+red[wb+3][3];
        float m0 = S0*0.00390625f, rs0 = rsqrtf(Q0*0.00390625f - m0*m0 + 1e-5f);
        float m1 = S1*0.00390625f, rs1 = rsqrtf(Q1*0.00390625f - m1*m1 + 1e-5f);
        float gc = lng[c], bc = lnb[c];
        mm[2*g][c]   = (hnew0 - m0)*rs0*gc + bc;
        mm[2*g+1][c] = (hnew1 - m1)*rs1*gc + bc;
    }
    __syncthreads();
    // MLP layer 1 (+ReLU)
    float h00 = b1[c], h01 = b1[c+256], h10 = b1[c], h11 = b1[c+256];
    for (int d = 0; d < 256; d++) {
        float w0 = W1[d*512 + c], w1 = W1[d*512 + c + 256];
        float m0v = mm[2*g][d], m1v = mm[2*g+1][d];
        h00 += m0v*w0; h01 += m0v*w1;
        h10 += m1v*w0; h11 += m1v*w1;
    }
    hid[2*g][c]       = fmaxf(h00, 0.f);
    hid[2*g][c+256]   = fmaxf(h01, 0.f);
    hid[2*g+1][c]     = fmaxf(h10, 0.f);
    hid[2*g+1][c+256] = fmaxf(h11, 0.f);
    __syncthreads();
    // MLP layer 2 + residual
    float o0 = b2[c], o1 = b2[c];
    for (int j = 0; j < 512; j++) {
        float w = W2[j*256 + c];
        o0 += hid[2*g][j] * w;
        o1 += hid[2*g+1][j] * w;
    }
    float out0 = hnew0 + o0;
    float out1 = hnew1 + o1;
    slots[(r0 + 2*g)*256 + c]     = out0;
    slots[(r0 + 2*g + 1)*256 + c] = out1;
    if (last) {
        outp[(r0 + 2*g)*256 + c]     = out0;
        outp[(r0 + 2*g + 1)*256 + c] = out1;
    }
}

extern "C" void kernel_launch(void* const* d_in, const int* in_sizes, int n_in,
                              void* d_out, int out_size, void* d_ws, size_t ws_size,
                              hipStream_t stream) {
    const float* inputs = (const float*)d_in[0];
    const float* noise  = (const float*)d_in[1];
    const float* mu     = (const float*)d_in[2];
    const float* sig    = (const float*)d_in[3];
    const float* lnig   = (const float*)d_in[4];
    const float* lnib   = (const float*)d_in[5];
    const float* lnsg   = (const float*)d_in[6];
    const float* lnsb   = (const float*)d_in[7];
    const float* lnmg   = (const float*)d_in[8];
    const float* lnmb   = (const float*)d_in[9];
    const float* Wq     = (const float*)d_in[10];
    const float* bq     = (const float*)d_in[11];
    const float* Wk     = (const float*)d_in[12];
    const float* bk     = (const float*)d_in[13];
    const float* Wv     = (const float*)d_in[14];
    const float* bv     = (const float*)d_in[15];
    const float* Wih    = (const float*)d_in[16];
    const float* Whh    = (const float*)d_in[17];
    const float* bih    = (const float*)d_in[18];
    const float* bhh    = (const float*)d_in[19];
    const float* W1     = (const float*)d_in[20];
    const float* b1     = (const float*)d_in[21];
    const float* W2     = (const float*)d_in[22];
    const float* b2     = (const float*)d_in[23];

    char* ws = (char*)d_ws;
    unsigned short* lnx = (unsigned short*)ws;
    size_t off = (size_t)NB * NPOS * HIDD * 2;                        // 64 MB
    unsigned short* qk = (unsigned short*)(ws + off); off += (size_t)NB*NSLOT*HIDD*2;
    float* qbk  = (float*)(ws + off); off += (size_t)NB*NSLOT*4;
    float* U    = (float*)(ws + off); off += (size_t)NB*NSLOT*HIDD*4;
    float* den  = (float*)(ws + off); off += (size_t)NB*NSLOT*4;
    float* slots= (float*)(ws + off); off += (size_t)NB*NSLOT*DDIM*4;

    k_ln_in<<<NB*NPOS/4, 256, 0, stream>>>(inputs, lnig, lnib, lnx);
    for (int it = 0; it < 3; it++) {
        k_pre<<<NB, 256, 0, stream>>>(noise, mu, sig, lnsg, lnsb, Wq, bq, Wk, bk,
                                      slots, qk, qbk, U, den, it);
        k_stream<<<NB*16, 256, 0, stream>>>(lnx, qk, qbk, U, den);
        k_post<<<NB*2, 512, 0, stream>>>(U, den, Wv, bv, Wih, Whh, bih, bhh,
                                         lnmg, lnmb, W1, b1, W2, b2,
                                         slots, (float*)d_out, it == 2 ? 1 : 0);
    }
}

// Round 2
// 391.369 us; speedup vs baseline: 3.3552x; 3.3552x over previous
//
#include <hip/hip_runtime.h>
#include <hip/hip_bf16.h>

#define NB 32
#define NPOS 4096
#define NSLOT 8
#define HIDD 256
#define DDIM 256
#define SCALE_F 0.0625f
#define EPS_F 1e-8f
#define NCHUNK 32     // chunks per batch (k_stream grid = NB*NCHUNK)
#define CPOS 128      // positions per chunk
#define TPOS 32       // positions per tile (2 waves x 16)

typedef __attribute__((ext_vector_type(4))) float f32x4;
typedef __attribute__((ext_vector_type(8))) short s16x8;
typedef __attribute__((ext_vector_type(2))) unsigned int u32x2;

__device__ __forceinline__ unsigned short f2bf(float f) {
    unsigned int x = __float_as_uint(f);
    x = (x + 0x7fffu + ((x >> 16) & 1u)) >> 16;
    return (unsigned short)x;
}

// ---------------- LayerNorm(inputs) -> bf16, one wave per row ----------------
__global__ __launch_bounds__(256) void k_ln_in(
        const float* __restrict__ x, const float* __restrict__ g,
        const float* __restrict__ b, unsigned short* __restrict__ lnx) {
    int lane = threadIdx.x & 63;
    int wave = threadIdx.x >> 6;
    long row = (long)blockIdx.x * 4 + wave;
    const float4* xr = (const float4*)(x + row * 256);
    float4 v = xr[lane];
    float s = v.x + v.y + v.z + v.w;
    float sq = v.x * v.x + v.y * v.y + v.z * v.z + v.w * v.w;
    #pragma unroll
    for (int m = 32; m; m >>= 1) { s += __shfl_xor(s, m); sq += __shfl_xor(sq, m); }
    float mean = s * 0.00390625f;
    float rstd = rsqrtf(sq * 0.00390625f - mean * mean + 1e-5f);
    const float4 gg = ((const float4*)g)[lane];
    const float4 bb = ((const float4*)b)[lane];
    ushort4 o;
    o.x = f2bf((v.x - mean) * rstd * gg.x + bb.x);
    o.y = f2bf((v.y - mean) * rstd * gg.y + bb.y);
    o.z = f2bf((v.z - mean) * rstd * gg.z + bb.z);
    o.w = f2bf((v.w - mean) * rstd * gg.w + bb.w);
    ((ushort4*)(lnx + row * 256))[lane] = o;
}

// ---- shared tail: LN(slot rows) -> q -> qbk, qk   (block = 2 rows, 256 thr) ----
__device__ __forceinline__ void qk_tail(
        float v0, float v1, int b, int s0,
        const float* __restrict__ lng, const float* __restrict__ lnb,
        const float* __restrict__ Wq, const float* __restrict__ bq,
        const float* __restrict__ Wk, const float* __restrict__ bk,
        unsigned short* __restrict__ qkg, float* __restrict__ qbkg,
        float (*sh)[256], float (*red)[4]) {
    int c = threadIdx.x;
    float s_0 = v0, q_0 = v0 * v0, s_1 = v1, q_1 = v1 * v1;
    #pragma unroll
    for (int m = 32; m; m >>= 1) {
        s_0 += __shfl_xor(s_0, m); q_0 += __shfl_xor(q_0, m);
        s_1 += __shfl_xor(s_1, m); q_1 += __shfl_xor(q_1, m);
    }
    if ((c & 63) == 0) { int w = c >> 6; red[w][0]=s_0; red[w][1]=q_0; red[w][2]=s_1; red[w][3]=q_1; }
    __syncthreads();
    float S0 = red[0][0]+red[1][0]+red[2][0]+red[3][0];
    float Q0 = red[0][1]+red[1][1]+red[2][1]+red[3][1];
    float S1 = red[0][2]+red[1][2]+red[2][2]+red[3][2];
    float Q1 = red[0][3]+red[1][3]+red[2][3]+red[3][3];
    float m0 = S0 * 0.00390625f, r0 = rsqrtf(Q0 * 0.00390625f - m0*m0 + 1e-5f);
    float m1 = S1 * 0.00390625f, r1 = rsqrtf(Q1 * 0.00390625f - m1*m1 + 1e-5f);
    float gc = lng[c], bc = lnb[c];
    sh[0][c] = (v0 - m0) * r0 * gc + bc;
    sh[1][c] = (v1 - m1) * r1 * gc + bc;
    __syncthreads();
    float qa0 = bq[c], qa1 = qa0;
    for (int h = 0; h < 256; h += 4) {
        float w0 = Wq[(h+0)*256+c], w1 = Wq[(h+1)*256+c];
        float w2 = Wq[(h+2)*256+c], w3 = Wq[(h+3)*256+c];
        float4 x0 = *(const float4*)&sh[0][h], x1 = *(const float4*)&sh[1][h];
        qa0 += x0.x*w0 + x0.y*w1 + x0.z*w2 + x0.w*w3;
        qa1 += x1.x*w0 + x1.y*w1 + x1.z*w2 + x1.w*w3;
    }
    __syncthreads();
    sh[0][c] = qa0; sh[1][c] = qa1;
    float bkc = bk[c];
    float p0 = qa0 * bkc, p1 = qa1 * bkc;
    #pragma unroll
    for (int m = 32; m; m >>= 1) { p0 += __shfl_xor(p0, m); p1 += __shfl_xor(p1, m); }
    __syncthreads();
    if ((c & 63) == 0) { int w = c >> 6; red[w][0] = p0; red[w][1] = p1; }
    __syncthreads();
    if (c < 2) qbkg[b*8 + s0 + c] = SCALE_F * (red[0][c]+red[1][c]+red[2][c]+red[3][c]);
    float k0 = 0.f, k1 = 0.f;
    const float* wkr = Wk + (long)c * 256;
    for (int d = 0; d < 256; d += 4) {
        float4 wk4 = *(const float4*)&wkr[d];
        float4 x0 = *(const float4*)&sh[0][d], x1 = *(const float4*)&sh[1][d];
        k0 += x0.x*wk4.x + x0.y*wk4.y + x0.z*wk4.z + x0.w*wk4.w;
        k1 += x1.x*wk4.x + x1.y*wk4.y + x1.z*wk4.z + x1.w*wk4.w;
    }
    qkg[(b*8 + s0    )*256 + c] = f2bf(SCALE_F * k0);
    qkg[(b*8 + s0 + 1)*256 + c] = f2bf(SCALE_F * k1);
}

// ---------------- iter-0: slots init + LN + q + qk ----------------
__global__ __launch_bounds__(256) void k_init(
        const float* __restrict__ noise, const float* __restrict__ mu,
        const float* __restrict__ sig, const float* __restrict__ lng,
        const float* __restrict__ lnb, const float* __restrict__ Wq,
        const float* __restrict__ bq, const float* __restrict__ Wk,
        const float* __restrict__ bk, float* __restrict__ slots,
        unsigned short* __restrict__ qkg, float* __restrict__ qbkg) {
    __shared__ float sh[2][256];
    __shared__ float red[4][4];
    int b = blockIdx.x >> 2, rp = blockIdx.x & 3;
    int s0 = rp * 2, r0 = b * 8 + s0;
    int c = threadIdx.x;
    float v0 = mu[c] + sig[c] * noise[r0*256 + c];
    float v1 = mu[c] + sig[c] * noise[(r0+1)*256 + c];
    slots[r0*256 + c] = v0;
    slots[(r0+1)*256 + c] = v1;
    qk_tail(v0, v1, b, s0, lng, lnb, Wq, bq, Wk, bk, qkg, qbkg, sh, red);
}

// ------- streaming attention: MFMA dots -> softmax(slot) -> MFMA updates -------
// grid = NB * NCHUNK blocks, 128 threads (2 waves), 4 tiles of 32 positions
__global__ __launch_bounds__(128) void k_stream(
        const unsigned short* __restrict__ lnx, const unsigned short* __restrict__ qk,
        const float* __restrict__ qbk, float* __restrict__ Upart,
        float* __restrict__ dpart) {
    __shared__ unsigned short xt[TPOS * 256];   // chunk-XOR swizzled
    __shared__ float Ured[8 * 256];
    __shared__ float dred[8];
    int b = blockIdx.x >> 5, ch = blockIdx.x & 31;
    int t = threadIdx.x;
    int l = t & 63, w = t >> 6;
    for (int i = t; i < 2048; i += 128) Ured[i] = 0.f;
    if (t < 8) dred[t] = 0.f;
    int slot = l & 15, g = l >> 4;
    // qk B-fragments in registers (slots 8..15 -> zero columns)
    s16x8 qkf[8];
    float qbkv = 0.f;
    if (slot < 8) {
        const unsigned short* qrow = qk + (b*8 + slot) * 256;
        #pragma unroll
        for (int hk = 0; hk < 8; hk++)
            qkf[hk] = *(const s16x8*)(qrow + hk*32 + 8*g);
        qbkv = qbk[b*8 + slot];
    } else {
        #pragma unroll
        for (int hk = 0; hk < 8; hk++) qkf[hk] = (s16x8)0;
    }
    f32x4 uacc[16];
    #pragma unroll
    for (int i = 0; i < 16; i++) uacc[i] = (f32x4)0.f;
    float dreg = 0.f;
    int gbase = (b * NPOS + ch * CPOS) * 256;
    int pw = w * 16;
    __syncthreads();
    for (int tile = 0; tile < 4; tile++) {
        // stage 32 pos x 256 h bf16 with chunk-XOR swizzle
        #pragma unroll
        for (int i = 0; i < 8; i++) {
            int c = t + 128 * i;
            int p = c >> 5, hc = c & 31;
            int4 v = *(const int4*)(lnx + gbase + (tile*TPOS + p)*256 + hc*8);
            *(int4*)&xt[p*256 + ((hc ^ (p & 15)) << 3)] = v;
        }
        __syncthreads();
        // dots^T: D[pos][slot], lane -> slot = l&15, pos = pw + 4*g + r
        f32x4 acc = (f32x4)0.f;
        {
            int prow = pw + (l & 15);
            const unsigned short* xrow = &xt[prow * 256];
            int sw = prow & 15;
            #pragma unroll
            for (int hk = 0; hk < 8; hk++) {
                s16x8 a = *(const s16x8*)(xrow + (((hk*4 + g) ^ sw) << 3));
                acc = __builtin_amdgcn_mfma_f32_16x16x32_bf16(a, qkf[hk], acc, 0, 0, 0);
            }
        }
        // softmax over 8 slots (lanes l&7 butterfly), per position-reg
        float at[4];
        #pragma unroll
        for (int r = 0; r < 4; r++) {
            float v = acc[r] + qbkv;
            float m = v;
            m = fmaxf(m, __shfl_xor(m, 1));
            m = fmaxf(m, __shfl_xor(m, 2));
            m = fmaxf(m, __shfl_xor(m, 4));
            float e = __expf(v - m);
            float sum = e;
            sum += __shfl_xor(sum, 1);
            sum += __shfl_xor(sum, 2);
            sum += __shfl_xor(sum, 4);
            float a = e / sum;
            at[r] = a;
            dreg += a;
        }
        // attn fragment == A-fragment of 16x16x16 (slot = l&15, k = 4g+j)
        u32x2 a2;
        a2.x = (unsigned)f2bf(at[0]) | ((unsigned)f2bf(at[1]) << 16);
        a2.y = (unsigned)f2bf(at[2]) | ((unsigned)f2bf(at[3]) << 16);
        // updates: U[slot][h] += sum_pos attn * x   (16 h-chunks of 16)
        int p0 = pw + 4 * g;
        int hl = l & 7;
        #pragma unroll
        for (int hc = 0; hc < 16; hc++) {
            int hcol = hc * 2 + ((l & 15) >> 3);
            unsigned e0 = xt[(p0+0)*256 + ((hcol ^ ((p0+0) & 15)) << 3) + hl];
            unsigned e1 = xt[(p0+1)*256 + ((hcol ^ ((p0+1) & 15)) << 3) + hl];
            unsigned e2 = xt[(p0+2)*256 + ((hcol ^ ((p0+2) & 15)) << 3) + hl];
            unsigned e3 = xt[(p0+3)*256 + ((hcol ^ ((p0+3) & 15)) << 3) + hl];
            u32x2 b2;
            b2.x = e0 | (e1 << 16);
            b2.y = e2 | (e3 << 16);
            asm volatile("v_mfma_f32_16x16x16_bf16 %0, %1, %2, %0"
                         : "+v"(uacc[hc]) : "v"(a2), "v"(b2));
        }
        __syncthreads();
    }
    // block-level reduce: lanes with slot' = 4g+r < 8  (g < 2)
    if (g < 2) {
        #pragma unroll
        for (int hc = 0; hc < 16; hc++) {
            int h = hc * 16 + (l & 15);
            #pragma unroll
            for (int r = 0; r < 4; r++)
                atomicAdd(&Ured[(4*g + r)*256 + h], uacc[hc][r]);
        }
    }
    dreg += __shfl_xor(dreg, 16);
    dreg += __shfl_xor(dreg, 32);
    if (slot < 8 && g == 0) atomicAdd(&dred[slot], dreg);
    __syncthreads();
    float* up = Upart + (long)(b * NCHUNK + ch) * 2048;
    for (int i = t; i < 2048; i += 128) up[i] = Ured[i];
    if (t < 8) dpart[(b * NCHUNK + ch) * 8 + t] = dred[t];
}

// ---- Upart reduce -> Wv -> GRU -> LN -> MLP -> slots (+fused next-iter q/qk) ----
// grid = 128 blocks (2 rows each), 256 threads
__global__ __launch_bounds__(256) void k_post(
        const float* __restrict__ Upart, const float* __restrict__ dpart,
        const float* __restrict__ Wv, const float* __restrict__ bv,
        const float* __restrict__ Wih, const float* __restrict__ Whh,
        const float* __restrict__ bih, const float* __restrict__ bhh,
        const float* __restrict__ lnmg, const float* __restrict__ lnmb,
        const float* __restrict__ W1, const float* __restrict__ b1,
        const float* __restrict__ W2, const float* __restrict__ b2,
        const float* __restrict__ lnsg, const float* __restrict__ lnsb,
        const float* __restrict__ Wq, const float* __restrict__ bq,
        const float* __restrict__ Wk, const float* __restrict__ bk,
        float* __restrict__ slots, unsigned short* __restrict__ qkg,
        float* __restrict__ qbkg, float* __restrict__ outp, int last) {
    __shared__ float UsL[2][256], updL[2][256], mmL[2][256];
    __shared__ float hidL[2][512];
    __shared__ float red[4][4];
    int b = blockIdx.x >> 2, rp = blockIdx.x & 3;
    int s0 = rp * 2, r0 = b * 8 + s0;
    int c = threadIdx.x;
    float u0 = 0.f, u1 = 0.f, d0 = 0.f, d1 = 0.f;
    const float* ub = Upart + (long)b * NCHUNK * 2048;
    const float* db = dpart + b * NCHUNK * 8;
    for (int chk = 0; chk < NCHUNK; chk++) {
        u0 += ub[chk*2048 + s0*256 + c];
        u1 += ub[chk*2048 + (s0+1)*256 + c];
        d0 += db[chk*8 + s0];
        d1 += db[chk*8 + s0 + 1];
    }
    UsL[0][c] = u0; UsL[1][c] = u1;
    float sp0 = slots[r0*256 + c], sp1 = slots[(r0+1)*256 + c];
    __syncthreads();
    float dn0 = 1.f / (d0 + (float)NPOS * EPS_F);
    float dn1 = 1.f / (d1 + (float)NPOS * EPS_F);
    float ua0 = 0.f, ua1 = 0.f;
    for (int h = 0; h < 256; h += 4) {
        float w0 = Wv[(h+0)*256+c], w1 = Wv[(h+1)*256+c];
        float w2 = Wv[(h+2)*256+c], w3 = Wv[(h+3)*256+c];
        float4 x0 = *(const float4*)&UsL[0][h], x1 = *(const float4*)&UsL[1][h];
        ua0 += x0.x*w0 + x0.y*w1 + x0.z*w2 + x0.w*w3;
        ua1 += x1.x*w0 + x1.y*w1 + x1.z*w2 + x1.w*w3;
    }
    float up0 = ua0 * dn0 + bv[c], up1 = ua1 * dn1 + bv[c];
    updL[0][c] = up0; updL[1][c] = up1;
    // reuse UsL for slots-prev
    __syncthreads();
    UsL[0][c] = sp0; UsL[1][c] = sp1;
    __syncthreads();
    // GRU
    float gi0r = bih[c], gi0z = bih[c+256], gi0n = bih[c+512];
    float gi1r = gi0r, gi1z = gi0z, gi1n = gi0n;
    float gh0r = bhh[c], gh0z = bhh[c+256], gh0n = bhh[c+512];
    float gh1r = gh0r, gh1z = gh0z, gh1n = gh0n;
    for (int d = 0; d < 256; d++) {
        float uu0 = updL[0][d], uu1 = updL[1][d];
        float ss0 = UsL[0][d], ss1 = UsL[1][d];
        const float* wir = Wih + d * 768;
        const float* whr = Whh + d * 768;
        float wr = wir[c], wz = wir[c+256], wn = wir[c+512];
        gi0r += uu0*wr; gi0z += uu0*wz; gi0n += uu0*wn;
        gi1r += uu1*wr; gi1z += uu1*wz; gi1n += uu1*wn;
        float hr = whr[c], hz = whr[c+256], hn = whr[c+512];
        gh0r += ss0*hr; gh0z += ss0*hz; gh0n += ss0*hn;
        gh1r += ss1*hr; gh1z += ss1*hz; gh1n += ss1*hn;
    }
    float rg0 = 1.f/(1.f+__expf(-(gi0r+gh0r)));
    float zg0 = 1.f/(1.f+__expf(-(gi0z+gh0z)));
    float ng0 = tanhf(gi0n + rg0*gh0n);
    float hnew0 = (1.f - zg0)*ng0 + zg0*sp0;
    float rg1 = 1.f/(1.f+__expf(-(gi1r+gh1r)));
    float zg1 = 1.f/(1.f+__expf(-(gi1z+gh1z)));
    float ng1 = tanhf(gi1n + rg1*gh1n);
    float hnew1 = (1.f - zg1)*ng1 + zg1*sp1;
    // LN(hnew) for MLP
    {
        float s_0 = hnew0, q_0 = hnew0*hnew0, s_1 = hnew1, q_1 = hnew1*hnew1;
        #pragma unroll
        for (int m = 32; m; m >>= 1) {
            s_0 += __shfl_xor(s_0, m); q_0 += __shfl_xor(q_0, m);
            s_1 += __shfl_xor(s_1, m); q_1 += __shfl_xor(q_1, m);
        }
        if ((c & 63) == 0) { int w = c >> 6; red[w][0]=s_0; red[w][1]=q_0; red[w][2]=s_1; red[w][3]=q_1; }
        __syncthreads();
        float S0 = red[0][0]+red[1][0]+red[2][0]+red[3][0];
        float Q0 = red[0][1]+red[1][1]+red[2][1]+red[3][1];
        float S1 = red[0][2]+red[1][2]+red[2][2]+red[3][2];
        float Q1 = red[0][3]+red[1][3]+red[2][3]+red[3][3];
        float m0 = S0*0.00390625f, rs0 = rsqrtf(Q0*0.00390625f - m0*m0 + 1e-5f);
        float m1 = S1*0.00390625f, rs1 = rsqrtf(Q1*0.00390625f - m1*m1 + 1e-5f);
        float gc = lnmg[c], bc = lnmb[c];
        mmL[0][c] = (hnew0 - m0)*rs0*gc + bc;
        mmL[1][c] = (hnew1 - m1)*rs1*gc + bc;
    }
    __syncthreads();
    float h00 = b1[c], h01 = b1[c+256], h10 = b1[c], h11 = b1[c+256];
    for (int d = 0; d < 256; d++) {
        float w0 = W1[d*512 + c], w1 = W1[d*512 + c + 256];
        float mv0 = mmL[0][d], mv1 = mmL[1][d];
        h00 += mv0*w0; h01 += mv0*w1;
        h10 += mv1*w0; h11 += mv1*w1;
    }
    hidL[0][c] = fmaxf(h00, 0.f); hidL[0][c+256] = fmaxf(h01, 0.f);
    hidL[1][c] = fmaxf(h10, 0.f); hidL[1][c+256] = fmaxf(h11, 0.f);
    __syncthreads();
    float o0 = b2[c], o1 = b2[c];
    for (int j = 0; j < 512; j++) {
        float w = W2[j*256 + c];
        o0 += hidL[0][j]*w; o1 += hidL[1][j]*w;
    }
    float out0 = hnew0 + o0, out1 = hnew1 + o1;
    slots[r0*256 + c] = out0;
    slots[(r0+1)*256 + c] = out1;
    if (last) {
        outp[r0*256 + c] = out0;
        outp[(r0+1)*256 + c] = out1;
    } else {
        __syncthreads();
        qk_tail(out0, out1, b, s0, lnsg, lnsb, Wq, bq, Wk, bk, qkg, qbkg,
                (float (*)[256])UsL, red);
    }
}

extern "C" void kernel_launch(void* const* d_in, const int* in_sizes, int n_in,
                              void* d_out, int out_size, void* d_ws, size_t ws_size,
                              hipStream_t stream) {
    const float* inputs = (const float*)d_in[0];
    const float* noise  = (const float*)d_in[1];
    const float* mu     = (const float*)d_in[2];
    const float* sig    = (const float*)d_in[3];
    const float* lnig   = (const float*)d_in[4];
    const float* lnib   = (const float*)d_in[5];
    const float* lnsg   = (const float*)d_in[6];
    const float* lnsb   = (const float*)d_in[7];
    const float* lnmg   = (const float*)d_in[8];
    const float* lnmb   = (const float*)d_in[9];
    const float* Wq     = (const float*)d_in[10];
    const float* bq     = (const float*)d_in[11];
    const float* Wk     = (const float*)d_in[12];
    const float* bk     = (const float*)d_in[13];
    const float* Wv     = (const float*)d_in[14];
    const float* bv     = (const float*)d_in[15];
    const float* Wih    = (const float*)d_in[16];
    const float* Whh    = (const float*)d_in[17];
    const float* bih    = (const float*)d_in[18];
    const float* bhh    = (const float*)d_in[19];
    const float* W1     = (const float*)d_in[20];
    const float* b1     = (const float*)d_in[21];
    const float* W2     = (const float*)d_in[22];
    const float* b2     = (const float*)d_in[23];

    char* ws = (char*)d_ws;
    unsigned short* lnx = (unsigned short*)ws;
    size_t off = (size_t)NB * NPOS * HIDD * 2;                                   // 64 MB
    unsigned short* qkb = (unsigned short*)(ws + off); off += (size_t)NB*NSLOT*HIDD*2;
    float* qbk   = (float*)(ws + off); off += (size_t)NB*NSLOT*4;
    float* Upart = (float*)(ws + off); off += (size_t)NB*NCHUNK*NSLOT*HIDD*4;    // 8 MB
    float* dpart = (float*)(ws + off); off += (size_t)NB*NCHUNK*NSLOT*4;
    float* slots = (float*)(ws + off); off += (size_t)NB*NSLOT*DDIM*4;

    k_ln_in<<<NB*NPOS/4, 256, 0, stream>>>(inputs, lnig, lnib, lnx);
    k_init<<<NB*4, 256, 0, stream>>>(noise, mu, sig, lnsg, lnsb, Wq, bq, Wk, bk,
                                     slots, qkb, qbk);
    for (int it = 0; it < 3; it++) {
        k_stream<<<NB*NCHUNK, 128, 0, stream>>>(lnx, qkb, qbk, Upart, dpart);
        k_post<<<NB*4, 256, 0, stream>>>(Upart, dpart, Wv, bv, Wih, Whh, bih, bhh,
                                         lnmg, lnmb, W1, b1, W2, b2,
                                         lnsg, lnsb, Wq, bq, Wk, bk,
                                         slots, qkb, qbk, (float*)d_out,
                                         it == 2 ? 1 : 0);
    }
}

// Round 3
// 344.308 us; speedup vs baseline: 3.8138x; 1.1367x over previous
//
#include <hip/hip_runtime.h>
#include <hip/hip_bf16.h>

#define NB 32
#define NPOS 4096
#define NSLOT 8
#define HIDD 256
#define DDIM 256
#define SCALE_F 0.0625f
#define EPS_F 1e-8f
#define NCHUNK 32     // chunks per batch (k_stream grid = NB*NCHUNK)
#define CPOS 128      // positions per chunk
#define TPOS 32       // positions per tile (2 waves x 16)

typedef __attribute__((ext_vector_type(4))) float f32x4;
typedef __attribute__((ext_vector_type(8))) short s16x8;
typedef __attribute__((ext_vector_type(2))) unsigned int u32x2;

__device__ __forceinline__ unsigned short f2bf(float f) {
    unsigned int x = __float_as_uint(f);
    x = (x + 0x7fffu + ((x >> 16) & 1u)) >> 16;
    return (unsigned short)x;
}
__device__ __forceinline__ float bf_lo(unsigned u) { return __uint_as_float(u << 16); }
__device__ __forceinline__ float bf_hi(unsigned u) { return __uint_as_float(u & 0xffff0000u); }

// ---------------- LayerNorm(inputs) -> bf16, one wave per row ----------------
__global__ __launch_bounds__(256) void k_ln_in(
        const float* __restrict__ x, const float* __restrict__ g,
        const float* __restrict__ b, unsigned short* __restrict__ lnx) {
    int lane = threadIdx.x & 63;
    int wave = threadIdx.x >> 6;
    long row = (long)blockIdx.x * 4 + wave;
    const float4* xr = (const float4*)(x + row * 256);
    float4 v = xr[lane];
    float s = v.x + v.y + v.z + v.w;
    float sq = v.x * v.x + v.y * v.y + v.z * v.z + v.w * v.w;
    #pragma unroll
    for (int m = 32; m; m >>= 1) { s += __shfl_xor(s, m); sq += __shfl_xor(sq, m); }
    float mean = s * 0.00390625f;
    float rstd = rsqrtf(sq * 0.00390625f - mean * mean + 1e-5f);
    const float4 gg = ((const float4*)g)[lane];
    const float4 bb = ((const float4*)b)[lane];
    ushort4 o;
    o.x = f2bf((v.x - mean) * rstd * gg.x + bb.x);
    o.y = f2bf((v.y - mean) * rstd * gg.y + bb.y);
    o.z = f2bf((v.z - mean) * rstd * gg.z + bb.z);
    o.w = f2bf((v.w - mean) * rstd * gg.w + bb.w);
    ((ushort4*)(lnx + row * 256))[lane] = o;
}

// ---------------- weight pack: bf16 row-pair packed ----------------
__device__ __forceinline__ unsigned packrow(const float* __restrict__ W, int hp, int N, int c) {
    return (unsigned)f2bf(W[(2*hp)*N + c]) | ((unsigned)f2bf(W[(2*hp+1)*N + c]) << 16);
}

__global__ __launch_bounds__(256) void k_prep(
        const float* __restrict__ Wq, const float* __restrict__ Wk,
        const float* __restrict__ Wv, const float* __restrict__ Wih,
        const float* __restrict__ Whh, const float* __restrict__ W1,
        const float* __restrict__ W2,
        unsigned* __restrict__ WqP, unsigned* __restrict__ WkTP,
        unsigned* __restrict__ WvP, unsigned* __restrict__ WihP,
        unsigned* __restrict__ WhhP, unsigned* __restrict__ W1P,
        unsigned* __restrict__ W2P) {
    int i = blockIdx.x * 256 + threadIdx.x;   // grid = 384 blocks -> i < 98304
    if (i < 32768) {
        int hp = i >> 8, c = i & 255;
        WqP[i] = packrow(Wq, hp, 256, c);
        WvP[i] = packrow(Wv, hp, 256, c);
        // WkT[d][c] = Wk[c][d]; pack along d
        WkTP[i] = (unsigned)f2bf(Wk[c*256 + 2*hp]) | ((unsigned)f2bf(Wk[c*256 + 2*hp + 1]) << 16);
    }
    if (i < 65536) {
        int hp1 = i >> 9, c1 = i & 511;
        W1P[i] = packrow(W1, hp1, 512, c1);
        int hp2 = i >> 8, c2 = i & 255;
        W2P[i] = packrow(W2, hp2, 256, c2);
    }
    if (i < 98304) {
        int hp = i / 768, c = i % 768;
        WihP[i] = packrow(Wih, hp, 768, c);
        WhhP[i] = packrow(Whh, hp, 768, c);
    }
}

// ---- shared tail: LN(slot rows) -> q -> qbk, qk   (block = 2 rows, 256 thr) ----
__device__ __forceinline__ void qk_tail(
        float v0, float v1, int b, int s0,
        const float* __restrict__ lng, const float* __restrict__ lnb,
        const float* __restrict__ Wq, const float* __restrict__ bq,
        const float* __restrict__ Wk, const float* __restrict__ bk,
        unsigned short* __restrict__ qkg, float* __restrict__ qbkg,
        float (*sh)[256], float (*red)[4]) {
    int c = threadIdx.x;
    float s_0 = v0, q_0 = v0 * v0, s_1 = v1, q_1 = v1 * v1;
    #pragma unroll
    for (int m = 32; m; m >>= 1) {
        s_0 += __shfl_xor(s_0, m); q_0 += __shfl_xor(q_0, m);
        s_1 += __shfl_xor(s_1, m); q_1 += __shfl_xor(q_1, m);
    }
    if ((c & 63) == 0) { int w = c >> 6; red[w][0]=s_0; red[w][1]=q_0; red[w][2]=s_1; red[w][3]=q_1; }
    __syncthreads();
    float S0 = red[0][0]+red[1][0]+red[2][0]+red[3][0];
    float Q0 = red[0][1]+red[1][1]+red[2][1]+red[3][1];
    float S1 = red[0][2]+red[1][2]+red[2][2]+red[3][2];
    float Q1 = red[0][3]+red[1][3]+red[2][3]+red[3][3];
    float m0 = S0 * 0.00390625f, r0 = rsqrtf(Q0 * 0.00390625f - m0*m0 + 1e-5f);
    float m1 = S1 * 0.00390625f, r1 = rsqrtf(Q1 * 0.00390625f - m1*m1 + 1e-5f);
    float gc = lng[c], bc = lnb[c];
    sh[0][c] = (v0 - m0) * r0 * gc + bc;
    sh[1][c] = (v1 - m1) * r1 * gc + bc;
    __syncthreads();
    float qa0 = bq[c], qa1 = qa0;
    for (int h = 0; h < 256; h += 4) {
        float w0 = Wq[(h+0)*256+c], w1 = Wq[(h+1)*256+c];
        float w2 = Wq[(h+2)*256+c], w3 = Wq[(h+3)*256+c];
        float4 x0 = *(const float4*)&sh[0][h], x1 = *(const float4*)&sh[1][h];
        qa0 += x0.x*w0 + x0.y*w1 + x0.z*w2 + x0.w*w3;
        qa1 += x1.x*w0 + x1.y*w1 + x1.z*w2 + x1.w*w3;
    }
    __syncthreads();
    sh[0][c] = qa0; sh[1][c] = qa1;
    float bkc = bk[c];
    float p0 = qa0 * bkc, p1 = qa1 * bkc;
    #pragma unroll
    for (int m = 32; m; m >>= 1) { p0 += __shfl_xor(p0, m); p1 += __shfl_xor(p1, m); }
    __syncthreads();
    if ((c & 63) == 0) { int w = c >> 6; red[w][0] = p0; red[w][1] = p1; }
    __syncthreads();
    if (c < 2) qbkg[b*8 + s0 + c] = SCALE_F * (red[0][c]+red[1][c]+red[2][c]+red[3][c]);
    float k0 = 0.f, k1 = 0.f;
    const float* wkr = Wk + (long)c * 256;
    for (int d = 0; d < 256; d += 4) {
        float4 wk4 = *(const float4*)&wkr[d];
        float4 x0 = *(const float4*)&sh[0][d], x1 = *(const float4*)&sh[1][d];
        k0 += x0.x*wk4.x + x0.y*wk4.y + x0.z*wk4.z + x0.w*wk4.w;
        k1 += x1.x*wk4.x + x1.y*wk4.y + x1.z*wk4.z + x1.w*wk4.w;
    }
    qkg[(b*8 + s0    )*256 + c] = f2bf(SCALE_F * k0);
    qkg[(b*8 + s0 + 1)*256 + c] = f2bf(SCALE_F * k1);
}

// ---------------- iter-0: slots init + LN + q + qk ----------------
__global__ __launch_bounds__(256) void k_init(
        const float* __restrict__ noise, const float* __restrict__ mu,
        const float* __restrict__ sig, const float* __restrict__ lng,
        const float* __restrict__ lnb, const float* __restrict__ Wq,
        const float* __restrict__ bq, const float* __restrict__ Wk,
        const float* __restrict__ bk, float* __restrict__ slots,
        unsigned short* __restrict__ qkg, float* __restrict__ qbkg) {
    __shared__ float sh[2][256];
    __shared__ float red[4][4];
    int b = blockIdx.x >> 2, rp = blockIdx.x & 3;
    int s0 = rp * 2, r0 = b * 8 + s0;
    int c = threadIdx.x;
    float v0 = mu[c] + sig[c] * noise[r0*256 + c];
    float v1 = mu[c] + sig[c] * noise[(r0+1)*256 + c];
    slots[r0*256 + c] = v0;
    slots[(r0+1)*256 + c] = v1;
    qk_tail(v0, v1, b, s0, lng, lnb, Wq, bq, Wk, bk, qkg, qbkg, sh, red);
}

// ------- streaming attention: MFMA dots -> softmax(slot) -> MFMA updates -------
// grid = NB * NCHUNK blocks, 128 threads (2 waves), 4 tiles of 32 positions
__global__ __launch_bounds__(128) void k_stream(
        const unsigned short* __restrict__ lnx, const unsigned short* __restrict__ qk,
        const float* __restrict__ qbk, float* __restrict__ Upart,
        float* __restrict__ dpart) {
    __shared__ unsigned short xt[TPOS * 256];   // chunk-XOR swizzled
    __shared__ float Ured[8 * 256];
    __shared__ float dred[8];
    int b = blockIdx.x >> 5, ch = blockIdx.x & 31;
    int t = threadIdx.x;
    int l = t & 63, w = t >> 6;
    for (int i = t; i < 2048; i += 128) Ured[i] = 0.f;
    if (t < 8) dred[t] = 0.f;
    int slot = l & 15, g = l >> 4;
    s16x8 qkf[8];
    float qbkv = 0.f;
    if (slot < 8) {
        const unsigned short* qrow = qk + (b*8 + slot) * 256;
        #pragma unroll
        for (int hk = 0; hk < 8; hk++)
            qkf[hk] = *(const s16x8*)(qrow + hk*32 + 8*g);
        qbkv = qbk[b*8 + slot];
    } else {
        #pragma unroll
        for (int hk = 0; hk < 8; hk++) qkf[hk] = (s16x8)0;
    }
    f32x4 uacc[16];
    #pragma unroll
    for (int i = 0; i < 16; i++) uacc[i] = (f32x4)0.f;
    float dreg = 0.f;
    int gbase = (b * NPOS + ch * CPOS) * 256;
    int pw = w * 16;
    __syncthreads();
    for (int tile = 0; tile < 4; tile++) {
        #pragma unroll
        for (int i = 0; i < 8; i++) {
            int c = t + 128 * i;
            int p = c >> 5, hc = c & 31;
            int4 v = *(const int4*)(lnx + gbase + (tile*TPOS + p)*256 + hc*8);
            *(int4*)&xt[p*256 + ((hc ^ (p & 15)) << 3)] = v;
        }
        __syncthreads();
        f32x4 acc = (f32x4)0.f;
        {
            int prow = pw + (l & 15);
            const unsigned short* xrow = &xt[prow * 256];
            int sw = prow & 15;
            #pragma unroll
            for (int hk = 0; hk < 8; hk++) {
                s16x8 a = *(const s16x8*)(xrow + (((hk*4 + g) ^ sw) << 3));
                acc = __builtin_amdgcn_mfma_f32_16x16x32_bf16(a, qkf[hk], acc, 0, 0, 0);
            }
        }
        float at[4];
        #pragma unroll
        for (int r = 0; r < 4; r++) {
            float v = acc[r] + qbkv;
            float m = v;
            m = fmaxf(m, __shfl_xor(m, 1));
            m = fmaxf(m, __shfl_xor(m, 2));
            m = fmaxf(m, __shfl_xor(m, 4));
            float e = __expf(v - m);
            float sum = e;
            sum += __shfl_xor(sum, 1);
            sum += __shfl_xor(sum, 2);
            sum += __shfl_xor(sum, 4);
            float a = e / sum;
            at[r] = a;
            dreg += a;
        }
        u32x2 a2;
        a2.x = (unsigned)f2bf(at[0]) | ((unsigned)f2bf(at[1]) << 16);
        a2.y = (unsigned)f2bf(at[2]) | ((unsigned)f2bf(at[3]) << 16);
        int p0 = pw + 4 * g;
        int hl = l & 7;
        #pragma unroll
        for (int hc = 0; hc < 16; hc++) {
            int hcol = hc * 2 + ((l & 15) >> 3);
            unsigned e0 = xt[(p0+0)*256 + ((hcol ^ ((p0+0) & 15)) << 3) + hl];
            unsigned e1 = xt[(p0+1)*256 + ((hcol ^ ((p0+1) & 15)) << 3) + hl];
            unsigned e2 = xt[(p0+2)*256 + ((hcol ^ ((p0+2) & 15)) << 3) + hl];
            unsigned e3 = xt[(p0+3)*256 + ((hcol ^ ((p0+3) & 15)) << 3) + hl];
            u32x2 b2;
            b2.x = e0 | (e1 << 16);
            b2.y = e2 | (e3 << 16);
            asm volatile("v_mfma_f32_16x16x16_bf16 %0, %1, %2, %0"
                         : "+v"(uacc[hc]) : "v"(a2), "v"(b2));
        }
        __syncthreads();
    }
    if (g < 2) {
        #pragma unroll
        for (int hc = 0; hc < 16; hc++) {
            int h = hc * 16 + (l & 15);
            #pragma unroll
            for (int r = 0; r < 4; r++)
                atomicAdd(&Ured[(4*g + r)*256 + h], uacc[hc][r]);
        }
    }
    dreg += __shfl_xor(dreg, 16);
    dreg += __shfl_xor(dreg, 32);
    if (slot < 8 && g == 0) atomicAdd(&dred[slot], dreg);
    __syncthreads();
    float* up = Upart + (long)(b * NCHUNK + ch) * 2048;
    for (int i = t; i < 2048; i += 128) up[i] = Ured[i];
    if (t < 8) dpart[(b * NCHUNK + ch) * 8 + t] = dred[t];
}

// ---- 512-thread duplicated-column layernorm (val duplicated across halves) ----
__device__ __forceinline__ float ln512(float v, int c, const float* __restrict__ g,
                                       const float* __restrict__ b, float (*red)[2]) {
    float s1 = v, s2 = v * v;
    #pragma unroll
    for (int m = 32; m; m >>= 1) { s1 += __shfl_xor(s1, m); s2 += __shfl_xor(s2, m); }
    int w = threadIdx.x >> 6;
    if ((threadIdx.x & 63) == 0) { red[w][0] = s1; red[w][1] = s2; }
    __syncthreads();
    float S = 0.f, Q = 0.f;
    #pragma unroll
    for (int i = 0; i < 8; i++) { S += red[i][0]; Q += red[i][1]; }
    float mean = S * (1.f/512.f);
    float rstd = rsqrtf(Q * (1.f/512.f) - mean*mean + 1e-5f);
    __syncthreads();
    return (v - mean) * rstd * g[c] + b[c];
}

// ---- k_post v3: 1 row/block, 512 threads, bf16 pair-packed weights ----
__global__ __launch_bounds__(512) void k_post(
        const float* __restrict__ Upart, const float* __restrict__ dpart,
        const unsigned* __restrict__ WvP, const float* __restrict__ bv,
        const unsigned* __restrict__ WihP, const unsigned* __restrict__ WhhP,
        const float* __restrict__ bih, const float* __restrict__ bhh,
        const float* __restrict__ lnmg, const float* __restrict__ lnmb,
        const unsigned* __restrict__ W1P, const float* __restrict__ b1,
        const unsigned* __restrict__ W2P, const float* __restrict__ b2,
        const float* __restrict__ lnsg, const float* __restrict__ lnsb,
        const unsigned* __restrict__ WqP, const float* __restrict__ bq,
        const unsigned* __restrict__ WkTP, const float* __restrict__ bk,
        float* __restrict__ slots, unsigned short* __restrict__ qkg,
        float* __restrict__ qbkg, float* __restrict__ outp, int last) {
    __shared__ float A[256];      // broadcast activation row
    __shared__ float B[256];      // slots prev
    __shared__ float P2[2][256];  // K-split partials
    __shared__ float G[6][256];   // gi r,z,n ; gh r,z,n
    __shared__ float H[512];      // mlp hidden
    __shared__ float red[8][2];
    __shared__ float scal[1];
    int r = blockIdx.x, b = r >> 3, s = r & 7;
    int t = threadIdx.x, c = t & 255, half = t >> 8;
    // ---- U reduce + denom
    {
        float u = 0.f;
        const float* ub = Upart + (long)b * NCHUNK * 2048 + s * 256 + c;
        #pragma unroll 4
        for (int chk = half*16; chk < half*16 + 16; chk++) u += ub[chk * 2048];
        P2[half][c] = u;
        if (t < 32) {
            float dv = dpart[(b*NCHUNK + t)*8 + s];
            #pragma unroll
            for (int m = 16; m; m >>= 1) dv += __shfl_xor(dv, m);
            if (t == 0) scal[0] = dv;
        }
    }
    __syncthreads();
    float dn = 1.f / (scal[0] + (float)NPOS * EPS_F);
    if (half == 0) A[c] = P2[0][c] + P2[1][c];
    else B[c] = slots[r*256 + c];
    __syncthreads();
    // ---- Wv
    {
        float acc = 0.f;
        const unsigned* wp = WvP + half*64*256 + c;
        const float* ap = A + half*128;
        #pragma unroll 4
        for (int i = 0; i < 64; i++) {
            unsigned wv = wp[i*256];
            acc += ap[2*i]*bf_lo(wv) + ap[2*i+1]*bf_hi(wv);
        }
        P2[half][c] = acc;
    }
    __syncthreads();
    float updc = (P2[0][c] + P2[1][c]) * dn + bv[c];
    if (half == 0) A[c] = updc;
    __syncthreads();
    // ---- GRU: half 0 -> gi = upd @ Wih ; half 1 -> gh = slots @ Whh
    {
        const float* src = half ? B : A;
        const unsigned* W = half ? WhhP : WihP;
        const float* bb = half ? bhh : bih;
        float ar = bb[c], az = bb[c+256], an = bb[c+512];
        #pragma unroll 2
        for (int hp = 0; hp < 128; hp++) {
            float a0 = src[2*hp], a1 = src[2*hp+1];
            unsigned w0 = W[hp*768 + c];
            unsigned w1 = W[hp*768 + c + 256];
            unsigned w2 = W[hp*768 + c + 512];
            ar += a0*bf_lo(w0) + a1*bf_hi(w0);
            az += a0*bf_lo(w1) + a1*bf_hi(w1);
            an += a0*bf_lo(w2) + a1*bf_hi(w2);
        }
        G[half*3+0][c] = ar; G[half*3+1][c] = az; G[half*3+2][c] = an;
    }
    __syncthreads();
    float spc = B[c];
    float rg = 1.f/(1.f + __expf(-(G[0][c] + G[3][c])));
    float zg = 1.f/(1.f + __expf(-(G[1][c] + G[4][c])));
    float ng = tanhf(G[2][c] + rg*G[5][c]);
    float hnew = (1.f - zg)*ng + zg*spc;
    // ---- LN -> mm
    float mmc = ln512(hnew, c, lnmg, lnmb, red);
    if (half == 0) A[c] = mmc;
    __syncthreads();
    // ---- MLP1: thread t = col j of 512
    {
        float hj = b1[t];
        #pragma unroll 4
        for (int hp = 0; hp < 128; hp++) {
            unsigned wv = W1P[hp*512 + t];
            hj += A[2*hp]*bf_lo(wv) + A[2*hp+1]*bf_hi(wv);
        }
        H[t] = fmaxf(hj, 0.f);
    }
    __syncthreads();
    // ---- MLP2 + residual
    {
        float acc = 0.f;
        const unsigned* wp = W2P + half*128*256 + c;
        const float* hb = H + half*256;
        #pragma unroll 4
        for (int i = 0; i < 128; i++) {
            unsigned wv = wp[i*256];
            acc += hb[2*i]*bf_lo(wv) + hb[2*i+1]*bf_hi(wv);
        }
        P2[half][c] = acc;
    }
    __syncthreads();
    float outc = hnew + P2[0][c] + P2[1][c] + b2[c];
    if (half == 0) {
        slots[r*256 + c] = outc;
        if (last) outp[r*256 + c] = outc;
    }
    if (last) return;
    // ---- LN(out) -> q -> qbk -> qk  (next-iteration attention inputs)
    float sc = ln512(outc, c, lnsg, lnsb, red);
    if (half == 0) A[c] = sc;
    __syncthreads();
    {
        float acc = 0.f;
        const unsigned* wp = WqP + half*64*256 + c;
        const float* ap = A + half*128;
        #pragma unroll 4
        for (int i = 0; i < 64; i++) {
            unsigned wv = wp[i*256];
            acc += ap[2*i]*bf_lo(wv) + ap[2*i+1]*bf_hi(wv);
        }
        P2[half][c] = acc;
    }
    __syncthreads();
    float qc = P2[0][c] + P2[1][c] + bq[c];
    // qbk: block-reduce qc*bk[c] over 512 threads = 2*sum
    {
        float v = qc * bk[c];
        #pragma unroll
        for (int m = 32; m; m >>= 1) v += __shfl_xor(v, m);
        int w = threadIdx.x >> 6;
        if ((threadIdx.x & 63) == 0) red[w][0] = v;
        __syncthreads();
        if (t == 0) {
            float S = 0.f;
            #pragma unroll
            for (int i = 0; i < 8; i++) S += red[i][0];
            qbkg[r] = SCALE_F * 0.5f * S;
        }
        __syncthreads();
    }
    if (half == 0) A[c] = qc;
    __syncthreads();
    {
        float acc = 0.f;
        const unsigned* wp = WkTP + half*64*256 + c;
        const float* ap = A + half*128;
        #pragma unroll 4
        for (int i = 0; i < 64; i++) {
            unsigned wv = wp[i*256];
            acc += ap[2*i]*bf_lo(wv) + ap[2*i+1]*bf_hi(wv);
        }
        P2[half][c] = acc;
    }
    __syncthreads();
    if (half == 0) qkg[r*256 + c] = f2bf(SCALE_F * (P2[0][c] + P2[1][c]));
}

extern "C" void kernel_launch(void* const* d_in, const int* in_sizes, int n_in,
                              void* d_out, int out_size, void* d_ws, size_t ws_size,
                              hipStream_t stream) {
    const float* inputs = (const float*)d_in[0];
    const float* noise  = (const float*)d_in[1];
    const float* mu     = (const float*)d_in[2];
    const float* sig    = (const float*)d_in[3];
    const float* lnig   = (const float*)d_in[4];
    const float* lnib   = (const float*)d_in[5];
    const float* lnsg   = (const float*)d_in[6];
    const float* lnsb   = (const float*)d_in[7];
    const float* lnmg   = (const float*)d_in[8];
    const float* lnmb   = (const float*)d_in[9];
    const float* Wq     = (const float*)d_in[10];
    const float* bq     = (const float*)d_in[11];
    const float* Wk     = (const float*)d_in[12];
    const float* bk     = (const float*)d_in[13];
    const float* Wv     = (const float*)d_in[14];
    const float* bv     = (const float*)d_in[15];
    const float* Wih    = (const float*)d_in[16];
    const float* Whh    = (const float*)d_in[17];
    const float* bih    = (const float*)d_in[18];
    const float* bhh    = (const float*)d_in[19];
    const float* W1     = (const float*)d_in[20];
    const float* b1     = (const float*)d_in[21];
    const float* W2     = (const float*)d_in[22];
    const float* b2     = (const float*)d_in[23];

    char* ws = (char*)d_ws;
    unsigned short* lnx = (unsigned short*)ws;
    size_t off = (size_t)NB * NPOS * HIDD * 2;                                   // 64 MB
    unsigned short* qkb = (unsigned short*)(ws + off); off += (size_t)NB*NSLOT*HIDD*2;
    float* qbk   = (float*)(ws + off); off += (size_t)NB*NSLOT*4;
    float* Upart = (float*)(ws + off); off += (size_t)NB*NCHUNK*NSLOT*HIDD*4;    // 8 MB
    float* dpart = (float*)(ws + off); off += (size_t)NB*NCHUNK*NSLOT*4;
    float* slots = (float*)(ws + off); off += (size_t)NB*NSLOT*DDIM*4;
    unsigned* WqP  = (unsigned*)(ws + off); off += 32768u*4;
    unsigned* WkTP = (unsigned*)(ws + off); off += 32768u*4;
    unsigned* WvP  = (unsigned*)(ws + off); off += 32768u*4;
    unsigned* WihP = (unsigned*)(ws + off); off += 98304u*4;
    unsigned* WhhP = (unsigned*)(ws + off); off += 98304u*4;
    unsigned* W1P  = (unsigned*)(ws + off); off += 65536u*4;
    unsigned* W2P  = (unsigned*)(ws + off); off += 65536u*4;

    k_prep<<<384, 256, 0, stream>>>(Wq, Wk, Wv, Wih, Whh, W1, W2,
                                    WqP, WkTP, WvP, WihP, WhhP, W1P, W2P);
    k_ln_in<<<NB*NPOS/4, 256, 0, stream>>>(inputs, lnig, lnib, lnx);
    k_init<<<NB*4, 256, 0, stream>>>(noise, mu, sig, lnsg, lnsb, Wq, bq, Wk, bk,
                                     slots, qkb, qbk);
    for (int it = 0; it < 3; it++) {
        k_stream<<<NB*NCHUNK, 128, 0, stream>>>(lnx, qkb, qbk, Upart, dpart);
        k_post<<<NB*NSLOT, 512, 0, stream>>>(Upart, dpart,
                                             WvP, bv, WihP, WhhP, bih, bhh,
                                             lnmg, lnmb, W1P, b1, W2P, b2,
                                             lnsg, lnsb, WqP, bq, WkTP, bk,
                                             slots, qkb, qbk, (float*)d_out,
                                             it == 2 ? 1 : 0);
    }
}

// Round 4
// 242.856 us; speedup vs baseline: 5.4069x; 1.4177x over previous
//
#include <hip/hip_runtime.h>
#include <hip/hip_bf16.h>

#define NB 32
#define NPOS 4096
#define NSLOT 8
#define HIDD 256
#define DDIM 256
#define SCALE_F 0.0625f
#define EPS_F 1e-8f
#define NCHUNK 32     // chunks per batch (k_stream grid = NB*NCHUNK)
#define CPOS 128      // positions per chunk
#define TPOS 32       // positions per tile (2 waves x 16)

typedef __attribute__((ext_vector_type(4))) float f32x4;
typedef __attribute__((ext_vector_type(8))) short s16x8;
typedef __attribute__((ext_vector_type(2))) unsigned int u32x2;

__device__ __forceinline__ unsigned short f2bf(float f) {
    unsigned int x = __float_as_uint(f);
    x = (x + 0x7fffu + ((x >> 16) & 1u)) >> 16;
    return (unsigned short)x;
}
__device__ __forceinline__ float bf_lo(unsigned u) { return __uint_as_float(u << 16); }
__device__ __forceinline__ float bf_hi(unsigned u) { return __uint_as_float(u & 0xffff0000u); }

// ---------------- LayerNorm(inputs) -> bf16, one wave per row ----------------
__global__ __launch_bounds__(256) void k_ln_in(
        const float* __restrict__ x, const float* __restrict__ g,
        const float* __restrict__ b, unsigned short* __restrict__ lnx) {
    int lane = threadIdx.x & 63;
    int wave = threadIdx.x >> 6;
    long row = (long)blockIdx.x * 4 + wave;
    const float4* xr = (const float4*)(x + row * 256);
    float4 v = xr[lane];
    float s = v.x + v.y + v.z + v.w;
    float sq = v.x * v.x + v.y * v.y + v.z * v.z + v.w * v.w;
    #pragma unroll
    for (int m = 32; m; m >>= 1) { s += __shfl_xor(s, m); sq += __shfl_xor(sq, m); }
    float mean = s * 0.00390625f;
    float rstd = rsqrtf(sq * 0.00390625f - mean * mean + 1e-5f);
    const float4 gg = ((const float4*)g)[lane];
    const float4 bb = ((const float4*)b)[lane];
    ushort4 o;
    o.x = f2bf((v.x - mean) * rstd * gg.x + bb.x);
    o.y = f2bf((v.y - mean) * rstd * gg.y + bb.y);
    o.z = f2bf((v.z - mean) * rstd * gg.z + bb.z);
    o.w = f2bf((v.w - mean) * rstd * gg.w + bb.w);
    ((ushort4*)(lnx + row * 256))[lane] = o;
}

// ---------------- weight pack: bf16 row-pair packed ----------------
__device__ __forceinline__ unsigned packrow(const float* __restrict__ W, int hp, int N, int c) {
    return (unsigned)f2bf(W[(2*hp)*N + c]) | ((unsigned)f2bf(W[(2*hp+1)*N + c]) << 16);
}

__global__ __launch_bounds__(256) void k_prep(
        const float* __restrict__ Wq, const float* __restrict__ Wk,
        const float* __restrict__ Wv, const float* __restrict__ Wih,
        const float* __restrict__ Whh, const float* __restrict__ W1,
        const float* __restrict__ W2,
        unsigned* __restrict__ WqP, unsigned* __restrict__ WkTP,
        unsigned* __restrict__ WvP, unsigned* __restrict__ WihP,
        unsigned* __restrict__ WhhP, unsigned* __restrict__ W1P,
        unsigned* __restrict__ W2P) {
    int i = blockIdx.x * 256 + threadIdx.x;   // grid = 384 blocks -> i < 98304
    if (i < 32768) {
        int hp = i >> 8, c = i & 255;
        WqP[i] = packrow(Wq, hp, 256, c);
        WvP[i] = packrow(Wv, hp, 256, c);
        WkTP[i] = (unsigned)f2bf(Wk[c*256 + 2*hp]) | ((unsigned)f2bf(Wk[c*256 + 2*hp + 1]) << 16);
    }
    if (i < 65536) {
        int hp1 = i >> 9, c1 = i & 511;
        W1P[i] = packrow(W1, hp1, 512, c1);
        int hp2 = i >> 8, c2 = i & 255;
        W2P[i] = packrow(W2, hp2, 256, c2);
    }
    if (i < 98304) {
        int hp = i / 768, c = i % 768;
        WihP[i] = packrow(Wih, hp, 768, c);
        WhhP[i] = packrow(Whh, hp, 768, c);
    }
}

// ---- shared tail: LN(slot rows) -> q -> qbk, qk   (block = 2 rows, 256 thr) ----
__device__ __forceinline__ void qk_tail(
        float v0, float v1, int b, int s0,
        const float* __restrict__ lng, const float* __restrict__ lnb,
        const float* __restrict__ Wq, const float* __restrict__ bq,
        const float* __restrict__ Wk, const float* __restrict__ bk,
        unsigned short* __restrict__ qkg, float* __restrict__ qbkg,
        float (*sh)[256], float (*red)[4]) {
    int c = threadIdx.x;
    float s_0 = v0, q_0 = v0 * v0, s_1 = v1, q_1 = v1 * v1;
    #pragma unroll
    for (int m = 32; m; m >>= 1) {
        s_0 += __shfl_xor(s_0, m); q_0 += __shfl_xor(q_0, m);
        s_1 += __shfl_xor(s_1, m); q_1 += __shfl_xor(q_1, m);
    }
    if ((c & 63) == 0) { int w = c >> 6; red[w][0]=s_0; red[w][1]=q_0; red[w][2]=s_1; red[w][3]=q_1; }
    __syncthreads();
    float S0 = red[0][0]+red[1][0]+red[2][0]+red[3][0];
    float Q0 = red[0][1]+red[1][1]+red[2][1]+red[3][1];
    float S1 = red[0][2]+red[1][2]+red[2][2]+red[3][2];
    float Q1 = red[0][3]+red[1][3]+red[2][3]+red[3][3];
    float m0 = S0 * 0.00390625f, r0 = rsqrtf(Q0 * 0.00390625f - m0*m0 + 1e-5f);
    float m1 = S1 * 0.00390625f, r1 = rsqrtf(Q1 * 0.00390625f - m1*m1 + 1e-5f);
    float gc = lng[c], bc = lnb[c];
    sh[0][c] = (v0 - m0) * r0 * gc + bc;
    sh[1][c] = (v1 - m1) * r1 * gc + bc;
    __syncthreads();
    float qa0 = bq[c], qa1 = qa0;
    for (int h = 0; h < 256; h += 4) {
        float w0 = Wq[(h+0)*256+c], w1 = Wq[(h+1)*256+c];
        float w2 = Wq[(h+2)*256+c], w3 = Wq[(h+3)*256+c];
        float4 x0 = *(const float4*)&sh[0][h], x1 = *(const float4*)&sh[1][h];
        qa0 += x0.x*w0 + x0.y*w1 + x0.z*w2 + x0.w*w3;
        qa1 += x1.x*w0 + x1.y*w1 + x1.z*w2 + x1.w*w3;
    }
    __syncthreads();
    sh[0][c] = qa0; sh[1][c] = qa1;
    float bkc = bk[c];
    float p0 = qa0 * bkc, p1 = qa1 * bkc;
    #pragma unroll
    for (int m = 32; m; m >>= 1) { p0 += __shfl_xor(p0, m); p1 += __shfl_xor(p1, m); }
    __syncthreads();
    if ((c & 63) == 0) { int w = c >> 6; red[w][0] = p0; red[w][1] = p1; }
    __syncthreads();
    if (c < 2) qbkg[b*8 + s0 + c] = SCALE_F * (red[0][c]+red[1][c]+red[2][c]+red[3][c]);
    float k0 = 0.f, k1 = 0.f;
    const float* wkr = Wk + (long)c * 256;
    for (int d = 0; d < 256; d += 4) {
        float4 wk4 = *(const float4*)&wkr[d];
        float4 x0 = *(const float4*)&sh[0][d], x1 = *(const float4*)&sh[1][d];
        k0 += x0.x*wk4.x + x0.y*wk4.y + x0.z*wk4.z + x0.w*wk4.w;
        k1 += x1.x*wk4.x + x1.y*wk4.y + x1.z*wk4.z + x1.w*wk4.w;
    }
    qkg[(b*8 + s0    )*256 + c] = f2bf(SCALE_F * k0);
    qkg[(b*8 + s0 + 1)*256 + c] = f2bf(SCALE_F * k1);
}

// ---------------- iter-0: slots init + LN + q + qk ----------------
__global__ __launch_bounds__(256) void k_init(
        const float* __restrict__ noise, const float* __restrict__ mu,
        const float* __restrict__ sig, const float* __restrict__ lng,
        const float* __restrict__ lnb, const float* __restrict__ Wq,
        const float* __restrict__ bq, const float* __restrict__ Wk,
        const float* __restrict__ bk, float* __restrict__ slots,
        unsigned short* __restrict__ qkg, float* __restrict__ qbkg) {
    __shared__ float sh[2][256];
    __shared__ float red[4][4];
    int b = blockIdx.x >> 2, rp = blockIdx.x & 3;
    int s0 = rp * 2, r0 = b * 8 + s0;
    int c = threadIdx.x;
    float v0 = mu[c] + sig[c] * noise[r0*256 + c];
    float v1 = mu[c] + sig[c] * noise[(r0+1)*256 + c];
    slots[r0*256 + c] = v0;
    slots[(r0+1)*256 + c] = v1;
    qk_tail(v0, v1, b, s0, lng, lnb, Wq, bq, Wk, bk, qkg, qbkg, sh, red);
}

// ------- streaming attention: MFMA dots -> softmax(slot) -> MFMA updates -------
// grid = NB * NCHUNK blocks, 128 threads (2 waves), 4 tiles of 32 positions
__global__ __launch_bounds__(128) void k_stream(
        const unsigned short* __restrict__ lnx, const unsigned short* __restrict__ qk,
        const float* __restrict__ qbk, float* __restrict__ Upart,
        float* __restrict__ dpart) {
    __shared__ unsigned short xt[TPOS * 256];   // chunk-XOR swizzled
    __shared__ float Ured[8 * 256];
    __shared__ float dred[8];
    int b = blockIdx.x >> 5, ch = blockIdx.x & 31;
    int t = threadIdx.x;
    int l = t & 63, w = t >> 6;
    for (int i = t; i < 2048; i += 128) Ured[i] = 0.f;
    if (t < 8) dred[t] = 0.f;
    int slot = l & 15, g = l >> 4;
    s16x8 qkf[8];
    float qbkv = 0.f;
    if (slot < 8) {
        const unsigned short* qrow = qk + (b*8 + slot) * 256;
        #pragma unroll
        for (int hk = 0; hk < 8; hk++)
            qkf[hk] = *(const s16x8*)(qrow + hk*32 + 8*g);
        qbkv = qbk[b*8 + slot];
    } else {
        #pragma unroll
        for (int hk = 0; hk < 8; hk++) qkf[hk] = (s16x8)0;
    }
    f32x4 uacc[16];
    #pragma unroll
    for (int i = 0; i < 16; i++) uacc[i] = (f32x4)0.f;
    float dreg = 0.f;
    int gbase = (b * NPOS + ch * CPOS) * 256;
    int pw = w * 16;
    __syncthreads();
    for (int tile = 0; tile < 4; tile++) {
        #pragma unroll
        for (int i = 0; i < 8; i++) {
            int c = t + 128 * i;
            int p = c >> 5, hc = c & 31;
            int4 v = *(const int4*)(lnx + gbase + (tile*TPOS + p)*256 + hc*8);
            *(int4*)&xt[p*256 + ((hc ^ (p & 15)) << 3)] = v;
        }
        __syncthreads();
        f32x4 acc = (f32x4)0.f;
        {
            int prow = pw + (l & 15);
            const unsigned short* xrow = &xt[prow * 256];
            int sw = prow & 15;
            #pragma unroll
            for (int hk = 0; hk < 8; hk++) {
                s16x8 a = *(const s16x8*)(xrow + (((hk*4 + g) ^ sw) << 3));
                acc = __builtin_amdgcn_mfma_f32_16x16x32_bf16(a, qkf[hk], acc, 0, 0, 0);
            }
        }
        float at[4];
        #pragma unroll
        for (int r = 0; r < 4; r++) {
            float v = acc[r] + qbkv;
            float m = v;
            m = fmaxf(m, __shfl_xor(m, 1));
            m = fmaxf(m, __shfl_xor(m, 2));
            m = fmaxf(m, __shfl_xor(m, 4));
            float e = __expf(v - m);
            float sum = e;
            sum += __shfl_xor(sum, 1);
            sum += __shfl_xor(sum, 2);
            sum += __shfl_xor(sum, 4);
            float a = e / sum;
            at[r] = a;
            dreg += a;
        }
        u32x2 a2;
        a2.x = (unsigned)f2bf(at[0]) | ((unsigned)f2bf(at[1]) << 16);
        a2.y = (unsigned)f2bf(at[2]) | ((unsigned)f2bf(at[3]) << 16);
        int p0 = pw + 4 * g;
        int hl = l & 7;
        #pragma unroll
        for (int hc = 0; hc < 16; hc++) {
            int hcol = hc * 2 + ((l & 15) >> 3);
            unsigned e0 = xt[(p0+0)*256 + ((hcol ^ ((p0+0) & 15)) << 3) + hl];
            unsigned e1 = xt[(p0+1)*256 + ((hcol ^ ((p0+1) & 15)) << 3) + hl];
            unsigned e2 = xt[(p0+2)*256 + ((hcol ^ ((p0+2) & 15)) << 3) + hl];
            unsigned e3 = xt[(p0+3)*256 + ((hcol ^ ((p0+3) & 15)) << 3) + hl];
            u32x2 b2;
            b2.x = e0 | (e1 << 16);
            b2.y = e2 | (e3 << 16);
            asm volatile("v_mfma_f32_16x16x16_bf16 %0, %1, %2, %0"
                         : "+v"(uacc[hc]) : "v"(a2), "v"(b2));
        }
        __syncthreads();
    }
    if (g < 2) {
        #pragma unroll
        for (int hc = 0; hc < 16; hc++) {
            int h = hc * 16 + (l & 15);
            #pragma unroll
            for (int r = 0; r < 4; r++)
                atomicAdd(&Ured[(4*g + r)*256 + h], uacc[hc][r]);
        }
    }
    dreg += __shfl_xor(dreg, 16);
    dreg += __shfl_xor(dreg, 32);
    if (slot < 8 && g == 0) atomicAdd(&dred[slot], dreg);
    __syncthreads();
    float* up = Upart + (long)(b * NCHUNK + ch) * 2048;
    for (int i = t; i < 2048; i += 128) up[i] = Ured[i];
    if (t < 8) dpart[(b * NCHUNK + ch) * 8 + t] = dred[t];
}

// ---- 1024-thread duplicated-column layernorm (each value appears 4x) ----
__device__ __forceinline__ float ln1024(float v, int c, const float* __restrict__ g,
                                        const float* __restrict__ b, float (*red)[2]) {
    float s1 = v, s2 = v * v;
    #pragma unroll
    for (int m = 32; m; m >>= 1) { s1 += __shfl_xor(s1, m); s2 += __shfl_xor(s2, m); }
    int w = threadIdx.x >> 6;
    if ((threadIdx.x & 63) == 0) { red[w][0] = s1; red[w][1] = s2; }
    __syncthreads();
    float S = 0.f, Q = 0.f;
    #pragma unroll
    for (int i = 0; i < 16; i++) { S += red[i][0]; Q += red[i][1]; }
    float mean = S * (1.f/1024.f);
    float rstd = rsqrtf(Q * (1.f/1024.f) - mean*mean + 1e-5f);
    __syncthreads();
    return (v - mean) * rstd * g[c] + b[c];
}

// ---- k_post v4: 1 row/block, 1024 threads, 4-way K-split on every GEMV ----
__global__ __launch_bounds__(1024) void k_post(
        const float* __restrict__ Upart, const float* __restrict__ dpart,
        const unsigned* __restrict__ WvP, const float* __restrict__ bv,
        const unsigned* __restrict__ WihP, const unsigned* __restrict__ WhhP,
        const float* __restrict__ bih, const float* __restrict__ bhh,
        const float* __restrict__ lnmg, const float* __restrict__ lnmb,
        const unsigned* __restrict__ W1P, const float* __restrict__ b1,
        const unsigned* __restrict__ W2P, const float* __restrict__ b2,
        const float* __restrict__ lnsg, const float* __restrict__ lnsb,
        const unsigned* __restrict__ WqP, const float* __restrict__ bq,
        const unsigned* __restrict__ WkTP, const float* __restrict__ bk,
        float* __restrict__ slots, unsigned short* __restrict__ qkg,
        float* __restrict__ qbkg, float* __restrict__ outp, int last) {
    __shared__ float A[256];       // broadcast activation row
    __shared__ float B[256];       // slots prev
    __shared__ float P4[4][256];   // 4-way K-split partials
    __shared__ float G[12][256];   // quarter-partial GRU accumulators
    __shared__ float H2[2][512];   // MLP1 K-split partials
    __shared__ float H[512];       // mlp hidden
    __shared__ float red[16][2];
    __shared__ float scal[1];
    int r = blockIdx.x, b = r >> 3, s = r & 7;
    int t = threadIdx.x, c = t & 255, q = t >> 8;
    // ---- P1: U partial reduce (quarter q sums 8 chunks) + denom + slots load
    {
        float u = 0.f;
        const float* ub = Upart + (long)b * NCHUNK * 2048 + s * 256 + c;
        #pragma unroll
        for (int i = 0; i < 8; i++) u += ub[(q * 8 + i) * 2048];
        P4[q][c] = u;
        if (q == 1) B[c] = slots[r * 256 + c];
        if (t < 32) {
            float dv = dpart[(b * NCHUNK + t) * 8 + s];
            #pragma unroll
            for (int m = 16; m; m >>= 1) dv += __shfl_xor(dv, m);
            if (t == 0) scal[0] = dv;
        }
    }
    __syncthreads();
    float dn = 1.f / (scal[0] + (float)NPOS * EPS_F);
    if (q == 0) A[c] = P4[0][c] + P4[1][c] + P4[2][c] + P4[3][c];
    __syncthreads();
    // ---- P2: Wv (K split 4: quarter q handles pairs [32q, 32q+32))
    {
        float acc = 0.f;
        const unsigned* wp = WvP + q * 32 * 256 + c;
        const float* ap = A + q * 64;
        #pragma unroll 8
        for (int i = 0; i < 32; i++) {
            unsigned wv = wp[i * 256];
            acc += ap[2*i] * bf_lo(wv) + ap[2*i+1] * bf_hi(wv);
        }
        P4[q][c] = acc;
    }
    __syncthreads();
    float updc = (P4[0][c] + P4[1][c] + P4[2][c] + P4[3][c]) * dn + bv[c];
    if (q == 0) A[c] = updc;
    __syncthreads();
    // ---- P3: GRU (quarters 0,1 -> gi over Wih K-halves; 2,3 -> gh over Whh)
    {
        const float* src = (q < 2) ? A : B;
        const unsigned* W = (q < 2) ? WihP : WhhP;
        int base = (q & 1) * 64;
        float ar = 0.f, az = 0.f, an = 0.f;
        #pragma unroll 4
        for (int i = 0; i < 64; i++) {
            int hp = base + i;
            float a0 = src[2*hp], a1 = src[2*hp+1];
            unsigned w0 = W[hp*768 + c];
            unsigned w1 = W[hp*768 + c + 256];
            unsigned w2 = W[hp*768 + c + 512];
            ar += a0*bf_lo(w0) + a1*bf_hi(w0);
            az += a0*bf_lo(w1) + a1*bf_hi(w1);
            an += a0*bf_lo(w2) + a1*bf_hi(w2);
        }
        G[q*3+0][c] = ar; G[q*3+1][c] = az; G[q*3+2][c] = an;
    }
    __syncthreads();
    float spc = B[c];
    float gir = bih[c]     + G[0][c] + G[3][c];
    float giz = bih[c+256] + G[1][c] + G[4][c];
    float gin = bih[c+512] + G[2][c] + G[5][c];
    float ghr = bhh[c]     + G[6][c] + G[9][c];
    float ghz = bhh[c+256] + G[7][c] + G[10][c];
    float ghn = bhh[c+512] + G[8][c] + G[11][c];
    float rg = 1.f/(1.f + __expf(-(gir+ghr)));
    float zg = 1.f/(1.f + __expf(-(giz+ghz)));
    float ng = tanhf(gin + rg*ghn);
    float hnew = (1.f - zg)*ng + zg*spc;
    // ---- LN -> mm
    float mmc = ln1024(hnew, c, lnmg, lnmb, red);
    if (q == 0) A[c] = mmc;
    __syncthreads();
    // ---- MLP1: j = t&511, K halves kh = t>>9
    {
        int j = t & 511, kh = t >> 9;
        float acc = 0.f;
        #pragma unroll 8
        for (int i = 0; i < 64; i++) {
            int hp = kh*64 + i;
            unsigned wv = W1P[hp*512 + j];
            acc += A[2*hp]*bf_lo(wv) + A[2*hp+1]*bf_hi(wv);
        }
        H2[kh][j] = acc;
    }
    __syncthreads();
    if (t < 512) H[t] = fmaxf(H2[0][t] + H2[1][t] + b1[t], 0.f);
    __syncthreads();
    // ---- MLP2 (K=512 -> 256 pairs, 64 per quarter)
    {
        float acc = 0.f;
        const unsigned* wp = W2P + q * 64 * 256 + c;
        const float* hb = H + q * 128;
        #pragma unroll 8
        for (int i = 0; i < 64; i++) {
            unsigned wv = wp[i * 256];
            acc += hb[2*i]*bf_lo(wv) + hb[2*i+1]*bf_hi(wv);
        }
        P4[q][c] = acc;
    }
    __syncthreads();
    float outc = hnew + P4[0][c] + P4[1][c] + P4[2][c] + P4[3][c] + b2[c];
    if (t < 256) {
        slots[r*256 + c] = outc;
        if (last) outp[r*256 + c] = outc;
    }
    if (last) return;
    // ---- LN(out) -> q -> qbk -> qk (next-iteration attention inputs)
    float sc = ln1024(outc, c, lnsg, lnsb, red);
    if (q == 0) A[c] = sc;
    __syncthreads();
    {
        float acc = 0.f;
        const unsigned* wp = WqP + q * 32 * 256 + c;
        const float* ap = A + q * 64;
        #pragma unroll 8
        for (int i = 0; i < 32; i++) {
            unsigned wv = wp[i * 256];
            acc += ap[2*i]*bf_lo(wv) + ap[2*i+1]*bf_hi(wv);
        }
        P4[q][c] = acc;
    }
    __syncthreads();
    float qc = P4[0][c] + P4[1][c] + P4[2][c] + P4[3][c] + bq[c];
    // qbk: block-reduce qc*bk[c] over 1024 threads = 4*sum
    {
        float v = qc * bk[c];
        #pragma unroll
        for (int m = 32; m; m >>= 1) v += __shfl_xor(v, m);
        int w = t >> 6;
        if ((t & 63) == 0) red[w][0] = v;
        __syncthreads();
        if (t == 0) {
            float S = 0.f;
            #pragma unroll
            for (int i = 0; i < 16; i++) S += red[i][0];
            qbkg[r] = SCALE_F * 0.25f * S;
        }
    }
    if (q == 0) A[c] = qc;
    __syncthreads();
    {
        float acc = 0.f;
        const unsigned* wp = WkTP + q * 32 * 256 + c;
        const float* ap = A + q * 64;
        #pragma unroll 8
        for (int i = 0; i < 32; i++) {
            unsigned wv = wp[i * 256];
            acc += ap[2*i]*bf_lo(wv) + ap[2*i+1]*bf_hi(wv);
        }
        P4[q][c] = acc;
    }
    __syncthreads();
    if (t < 256) qkg[r*256 + c] = f2bf(SCALE_F * (P4[0][c] + P4[1][c] + P4[2][c] + P4[3][c]));
}

extern "C" void kernel_launch(void* const* d_in, const int* in_sizes, int n_in,
                              void* d_out, int out_size, void* d_ws, size_t ws_size,
                              hipStream_t stream) {
    const float* inputs = (const float*)d_in[0];
    const float* noise  = (const float*)d_in[1];
    const float* mu     = (const float*)d_in[2];
    const float* sig    = (const float*)d_in[3];
    const float* lnig   = (const float*)d_in[4];
    const float* lnib   = (const float*)d_in[5];
    const float* lnsg   = (const float*)d_in[6];
    const float* lnsb   = (const float*)d_in[7];
    const float* lnmg   = (const float*)d_in[8];
    const float* lnmb   = (const float*)d_in[9];
    const float* Wq     = (const float*)d_in[10];
    const float* bq     = (const float*)d_in[11];
    const float* Wk     = (const float*)d_in[12];
    const float* bk     = (const float*)d_in[13];
    const float* Wv     = (const float*)d_in[14];
    const float* bv     = (const float*)d_in[15];
    const float* Wih    = (const float*)d_in[16];
    const float* Whh    = (const float*)d_in[17];
    const float* bih    = (const float*)d_in[18];
    const float* bhh    = (const float*)d_in[19];
    const float* W1     = (const float*)d_in[20];
    const float* b1     = (const float*)d_in[21];
    const float* W2     = (const float*)d_in[22];
    const float* b2     = (const float*)d_in[23];

    char* ws = (char*)d_ws;
    unsigned short* lnx = (unsigned short*)ws;
    size_t off = (size_t)NB * NPOS * HIDD * 2;                                   // 64 MB
    unsigned short* qkb = (unsigned short*)(ws + off); off += (size_t)NB*NSLOT*HIDD*2;
    float* qbk   = (float*)(ws + off); off += (size_t)NB*NSLOT*4;
    float* Upart = (float*)(ws + off); off += (size_t)NB*NCHUNK*NSLOT*HIDD*4;    // 8 MB
    float* dpart = (float*)(ws + off); off += (size_t)NB*NCHUNK*NSLOT*4;
    float* slots = (float*)(ws + off); off += (size_t)NB*NSLOT*DDIM*4;
    unsigned* WqP  = (unsigned*)(ws + off); off += 32768u*4;
    unsigned* WkTP = (unsigned*)(ws + off); off += 32768u*4;
    unsigned* WvP  = (unsigned*)(ws + off); off += 32768u*4;
    unsigned* WihP = (unsigned*)(ws + off); off += 98304u*4;
    unsigned* WhhP = (unsigned*)(ws + off); off += 98304u*4;
    unsigned* W1P  = (unsigned*)(ws + off); off += 65536u*4;
    unsigned* W2P  = (unsigned*)(ws + off); off += 65536u*4;

    k_prep<<<384, 256, 0, stream>>>(Wq, Wk, Wv, Wih, Whh, W1, W2,
                                    WqP, WkTP, WvP, WihP, WhhP, W1P, W2P);
    k_ln_in<<<NB*NPOS/4, 256, 0, stream>>>(inputs, lnig, lnib, lnx);
    k_init<<<NB*4, 256, 0, stream>>>(noise, mu, sig, lnsg, lnsb, Wq, bq, Wk, bk,
                                     slots, qkb, qbk);
    for (int it = 0; it < 3; it++) {
        k_stream<<<NB*NCHUNK, 128, 0, stream>>>(lnx, qkb, qbk, Upart, dpart);
        k_post<<<NB*NSLOT, 1024, 0, stream>>>(Upart, dpart,
                                              WvP, bv, WihP, WhhP, bih, bhh,
                                              lnmg, lnmb, W1P, b1, W2P, b2,
                                              lnsg, lnsb, WqP, bq, WkTP, bk,
                                              slots, qkb, qbk, (float*)d_out,
                                              it == 2 ? 1 : 0);
    }
}

// Round 6
// 236.641 us; speedup vs baseline: 5.5489x; 1.0263x over previous
//
#include <hip/hip_runtime.h>
#include <hip/hip_bf16.h>

#define NB 32
#define NPOS 4096
#define NSLOT 8
#define HIDD 256
#define DDIM 256
#define SCALE_F 0.0625f
#define EPS_F 1e-8f
#define NCHUNK 32     // chunks per batch (k_stream grid = NB*NCHUNK)
#define CPOS 128      // positions per chunk
#define TPOS 32       // positions per tile (2 waves x 16)

typedef __attribute__((ext_vector_type(4))) float f32x4;
typedef __attribute__((ext_vector_type(8))) short s16x8;
typedef __attribute__((ext_vector_type(2))) unsigned int u32x2;

__device__ __forceinline__ unsigned short f2bf(float f) {
    unsigned int x = __float_as_uint(f);
    x = (x + 0x7fffu + ((x >> 16) & 1u)) >> 16;
    return (unsigned short)x;
}
__device__ __forceinline__ float bf_lo(unsigned u) { return __uint_as_float(u << 16); }
__device__ __forceinline__ float bf_hi(unsigned u) { return __uint_as_float(u & 0xffff0000u); }

// one x4 FMA step: acc += a0*lo(wv) + a1*hi(wv) over 4 packed columns
__device__ __forceinline__ void fma4(f32x4& acc, uint4 wv, float a0, float a1) {
    acc[0] += a0 * bf_lo(wv.x) + a1 * bf_hi(wv.x);
    acc[1] += a0 * bf_lo(wv.y) + a1 * bf_hi(wv.y);
    acc[2] += a0 * bf_lo(wv.z) + a1 * bf_hi(wv.z);
    acc[3] += a0 * bf_lo(wv.w) + a1 * bf_hi(wv.w);
}

// ---------------- LayerNorm(inputs) -> bf16, one wave per row ----------------
__global__ __launch_bounds__(256) void k_ln_in(
        const float* __restrict__ x, const float* __restrict__ g,
        const float* __restrict__ b, unsigned short* __restrict__ lnx) {
    int lane = threadIdx.x & 63;
    int wave = threadIdx.x >> 6;
    long row = (long)blockIdx.x * 4 + wave;
    const float4* xr = (const float4*)(x + row * 256);
    float4 v = xr[lane];
    float s = v.x + v.y + v.z + v.w;
    float sq = v.x * v.x + v.y * v.y + v.z * v.z + v.w * v.w;
    #pragma unroll
    for (int m = 32; m; m >>= 1) { s += __shfl_xor(s, m); sq += __shfl_xor(sq, m); }
    float mean = s * 0.00390625f;
    float rstd = rsqrtf(sq * 0.00390625f - mean * mean + 1e-5f);
    const float4 gg = ((const float4*)g)[lane];
    const float4 bb = ((const float4*)b)[lane];
    ushort4 o;
    o.x = f2bf((v.x - mean) * rstd * gg.x + bb.x);
    o.y = f2bf((v.y - mean) * rstd * gg.y + bb.y);
    o.z = f2bf((v.z - mean) * rstd * gg.z + bb.z);
    o.w = f2bf((v.w - mean) * rstd * gg.w + bb.w);
    ((ushort4*)(lnx + row * 256))[lane] = o;
}

// ---------------- weight pack: bf16 row-pair packed ----------------
__device__ __forceinline__ unsigned packrow(const float* __restrict__ W, int hp, int N, int c) {
    return (unsigned)f2bf(W[(2*hp)*N + c]) | ((unsigned)f2bf(W[(2*hp+1)*N + c]) << 16);
}

__global__ __launch_bounds__(256) void k_prep(
        const float* __restrict__ Wq, const float* __restrict__ Wk,
        const float* __restrict__ Wv, const float* __restrict__ Wih,
        const float* __restrict__ Whh, const float* __restrict__ W1,
        const float* __restrict__ W2,
        unsigned* __restrict__ WqP, unsigned* __restrict__ WkTP,
        unsigned* __restrict__ WvP, unsigned* __restrict__ WihP,
        unsigned* __restrict__ WhhP, unsigned* __restrict__ W1P,
        unsigned* __restrict__ W2P) {
    int i = blockIdx.x * 256 + threadIdx.x;   // grid = 384 blocks -> i < 98304
    if (i < 32768) {
        int hp = i >> 8, c = i & 255;
        WqP[i] = packrow(Wq, hp, 256, c);
        WvP[i] = packrow(Wv, hp, 256, c);
        WkTP[i] = (unsigned)f2bf(Wk[c*256 + 2*hp]) | ((unsigned)f2bf(Wk[c*256 + 2*hp + 1]) << 16);
    }
    if (i < 65536) {
        int hp1 = i >> 9, c1 = i & 511;
        W1P[i] = packrow(W1, hp1, 512, c1);
        int hp2 = i >> 8, c2 = i & 255;
        W2P[i] = packrow(W2, hp2, 256, c2);
    }
    if (i < 98304) {
        int hp = i / 768, c = i % 768;
        WihP[i] = packrow(Wih, hp, 768, c);
        WhhP[i] = packrow(Whh, hp, 768, c);
    }
}

// ---- shared tail: LN(slot rows) -> q -> qbk, qk   (block = 2 rows, 256 thr) ----
__device__ __forceinline__ void qk_tail(
        float v0, float v1, int b, int s0,
        const float* __restrict__ lng, const float* __restrict__ lnb,
        const float* __restrict__ Wq, const float* __restrict__ bq,
        const float* __restrict__ Wk, const float* __restrict__ bk,
        unsigned short* __restrict__ qkg, float* __restrict__ qbkg,
        float (*sh)[256], float (*red)[4]) {
    int c = threadIdx.x;
    float s_0 = v0, q_0 = v0 * v0, s_1 = v1, q_1 = v1 * v1;
    #pragma unroll
    for (int m = 32; m; m >>= 1) {
        s_0 += __shfl_xor(s_0, m); q_0 += __shfl_xor(q_0, m);
        s_1 += __shfl_xor(s_1, m); q_1 += __shfl_xor(q_1, m);
    }
    if ((c & 63) == 0) { int w = c >> 6; red[w][0]=s_0; red[w][1]=q_0; red[w][2]=s_1; red[w][3]=q_1; }
    __syncthreads();
    float S0 = red[0][0]+red[1][0]+red[2][0]+red[3][0];
    float Q0 = red[0][1]+red[1][1]+red[2][1]+red[3][1];
    float S1 = red[0][2]+red[1][2]+red[2][2]+red[3][2];
    float Q1 = red[0][3]+red[1][3]+red[2][3]+red[3][3];
    float m0 = S0 * 0.00390625f, r0 = rsqrtf(Q0 * 0.00390625f - m0*m0 + 1e-5f);
    float m1 = S1 * 0.00390625f, r1 = rsqrtf(Q1 * 0.00390625f - m1*m1 + 1e-5f);
    float gc = lng[c], bc = lnb[c];
    sh[0][c] = (v0 - m0) * r0 * gc + bc;
    sh[1][c] = (v1 - m1) * r1 * gc + bc;
    __syncthreads();
    float qa0 = bq[c], qa1 = qa0;
    for (int h = 0; h < 256; h += 4) {
        float w0 = Wq[(h+0)*256+c], w1 = Wq[(h+1)*256+c];
        float w2 = Wq[(h+2)*256+c], w3 = Wq[(h+3)*256+c];
        float4 x0 = *(const float4*)&sh[0][h], x1 = *(const float4*)&sh[1][h];
        qa0 += x0.x*w0 + x0.y*w1 + x0.z*w2 + x0.w*w3;
        qa1 += x1.x*w0 + x1.y*w1 + x1.z*w2 + x1.w*w3;
    }
    __syncthreads();
    sh[0][c] = qa0; sh[1][c] = qa1;
    float bkc = bk[c];
    float p0 = qa0 * bkc, p1 = qa1 * bkc;
    #pragma unroll
    for (int m = 32; m; m >>= 1) { p0 += __shfl_xor(p0, m); p1 += __shfl_xor(p1, m); }
    __syncthreads();
    if ((c & 63) == 0) { int w = c >> 6; red[w][0] = p0; red[w][1] = p1; }
    __syncthreads();
    if (c < 2) qbkg[b*8 + s0 + c] = SCALE_F * (red[0][c]+red[1][c]+red[2][c]+red[3][c]);
    float k0 = 0.f, k1 = 0.f;
    const float* wkr = Wk + (long)c * 256;
    for (int d = 0; d < 256; d += 4) {
        float4 wk4 = *(const float4*)&wkr[d];
        float4 x0 = *(const float4*)&sh[0][d], x1 = *(const float4*)&sh[1][d];
        k0 += x0.x*wk4.x + x0.y*wk4.y + x0.z*wk4.z + x0.w*wk4.w;
        k1 += x1.x*wk4.x + x1.y*wk4.y + x1.z*wk4.z + x1.w*wk4.w;
    }
    qkg[(b*8 + s0    )*256 + c] = f2bf(SCALE_F * k0);
    qkg[(b*8 + s0 + 1)*256 + c] = f2bf(SCALE_F * k1);
}

// ---------------- iter-0: slots init + LN + q + qk ----------------
__global__ __launch_bounds__(256) void k_init(
        const float* __restrict__ noise, const float* __restrict__ mu,
        const float* __restrict__ sig, const float* __restrict__ lng,
        const float* __restrict__ lnb, const float* __restrict__ Wq,
        const float* __restrict__ bq, const float* __restrict__ Wk,
        const float* __restrict__ bk, float* __restrict__ slots,
        unsigned short* __restrict__ qkg, float* __restrict__ qbkg) {
    __shared__ float sh[2][256];
    __shared__ float red[4][4];
    int b = blockIdx.x >> 2, rp = blockIdx.x & 3;
    int s0 = rp * 2, r0 = b * 8 + s0;
    int c = threadIdx.x;
    float v0 = mu[c] + sig[c] * noise[r0*256 + c];
    float v1 = mu[c] + sig[c] * noise[(r0+1)*256 + c];
    slots[r0*256 + c] = v0;
    slots[(r0+1)*256 + c] = v1;
    qk_tail(v0, v1, b, s0, lng, lnb, Wq, bq, Wk, bk, qkg, qbkg, sh, red);
}

// ------- streaming attention: MFMA dots -> softmax(slot) -> MFMA updates -------
// grid = NB * NCHUNK blocks, 128 threads (2 waves), 4 tiles of 32 positions
__global__ __launch_bounds__(128) void k_stream(
        const unsigned short* __restrict__ lnx, const unsigned short* __restrict__ qk,
        const float* __restrict__ qbk, float* __restrict__ Upart,
        float* __restrict__ dpart) {
    __shared__ unsigned short xt[TPOS * 256];   // chunk-XOR swizzled
    __shared__ float Ured[8 * 256];
    __shared__ float dred[8];
    int b = blockIdx.x >> 5, ch = blockIdx.x & 31;
    int t = threadIdx.x;
    int l = t & 63, w = t >> 6;
    for (int i = t; i < 2048; i += 128) Ured[i] = 0.f;
    if (t < 8) dred[t] = 0.f;
    int slot = l & 15, g = l >> 4;
    s16x8 qkf[8];
    float qbkv = 0.f;
    if (slot < 8) {
        const unsigned short* qrow = qk + (b*8 + slot) * 256;
        #pragma unroll
        for (int hk = 0; hk < 8; hk++)
            qkf[hk] = *(const s16x8*)(qrow + hk*32 + 8*g);
        qbkv = qbk[b*8 + slot];
    } else {
        #pragma unroll
        for (int hk = 0; hk < 8; hk++) qkf[hk] = (s16x8)0;
    }
    f32x4 uacc[16];
    #pragma unroll
    for (int i = 0; i < 16; i++) uacc[i] = (f32x4)0.f;
    float dreg = 0.f;
    int gbase = (b * NPOS + ch * CPOS) * 256;
    int pw = w * 16;
    __syncthreads();
    for (int tile = 0; tile < 4; tile++) {
        #pragma unroll
        for (int i = 0; i < 8; i++) {
            int c = t + 128 * i;
            int p = c >> 5, hc = c & 31;
            int4 v = *(const int4*)(lnx + gbase + (tile*TPOS + p)*256 + hc*8);
            *(int4*)&xt[p*256 + ((hc ^ (p & 15)) << 3)] = v;
        }
        __syncthreads();
        f32x4 acc = (f32x4)0.f;
        {
            int prow = pw + (l & 15);
            const unsigned short* xrow = &xt[prow * 256];
            int sw = prow & 15;
            #pragma unroll
            for (int hk = 0; hk < 8; hk++) {
                s16x8 a = *(const s16x8*)(xrow + (((hk*4 + g) ^ sw) << 3));
                acc = __builtin_amdgcn_mfma_f32_16x16x32_bf16(a, qkf[hk], acc, 0, 0, 0);
            }
        }
        float at[4];
        #pragma unroll
        for (int r = 0; r < 4; r++) {
            float v = acc[r] + qbkv;
            float m = v;
            m = fmaxf(m, __shfl_xor(m, 1));
            m = fmaxf(m, __shfl_xor(m, 2));
            m = fmaxf(m, __shfl_xor(m, 4));
            float e = __expf(v - m);
            float sum = e;
            sum += __shfl_xor(sum, 1);
            sum += __shfl_xor(sum, 2);
            sum += __shfl_xor(sum, 4);
            float a = e / sum;
            at[r] = a;
            dreg += a;
        }
        u32x2 a2;
        a2.x = (unsigned)f2bf(at[0]) | ((unsigned)f2bf(at[1]) << 16);
        a2.y = (unsigned)f2bf(at[2]) | ((unsigned)f2bf(at[3]) << 16);
        int p0 = pw + 4 * g;
        int hl = l & 7;
        #pragma unroll
        for (int hc = 0; hc < 16; hc++) {
            int hcol = hc * 2 + ((l & 15) >> 3);
            unsigned e0 = xt[(p0+0)*256 + ((hcol ^ ((p0+0) & 15)) << 3) + hl];
            unsigned e1 = xt[(p0+1)*256 + ((hcol ^ ((p0+1) & 15)) << 3) + hl];
            unsigned e2 = xt[(p0+2)*256 + ((hcol ^ ((p0+2) & 15)) << 3) + hl];
            unsigned e3 = xt[(p0+3)*256 + ((hcol ^ ((p0+3) & 15)) << 3) + hl];
            u32x2 b2;
            b2.x = e0 | (e1 << 16);
            b2.y = e2 | (e3 << 16);
            asm volatile("v_mfma_f32_16x16x16_bf16 %0, %1, %2, %0"
                         : "+v"(uacc[hc]) : "v"(a2), "v"(b2));
        }
        __syncthreads();
    }
    if (g < 2) {
        #pragma unroll
        for (int hc = 0; hc < 16; hc++) {
            int h = hc * 16 + (l & 15);
            #pragma unroll
            for (int r = 0; r < 4; r++)
                atomicAdd(&Ured[(4*g + r)*256 + h], uacc[hc][r]);
        }
    }
    dreg += __shfl_xor(dreg, 16);
    dreg += __shfl_xor(dreg, 32);
    if (slot < 8 && g == 0) atomicAdd(&dred[slot], dreg);
    __syncthreads();
    float* up = Upart + (long)(b * NCHUNK + ch) * 2048;
    for (int i = t; i < 2048; i += 128) up[i] = Ured[i];
    if (t < 8) dpart[(b * NCHUNK + ch) * 8 + t] = dred[t];
}

// ---- 1024-thread duplicated-column layernorm (each value appears 4x) ----
__device__ __forceinline__ float ln1024(float v, int c, const float* __restrict__ g,
                                        const float* __restrict__ b, float (*red)[2]) {
    float s1 = v, s2 = v * v;
    #pragma unroll
    for (int m = 32; m; m >>= 1) { s1 += __shfl_xor(s1, m); s2 += __shfl_xor(s2, m); }
    int w = threadIdx.x >> 6;
    if ((threadIdx.x & 63) == 0) { red[w][0] = s1; red[w][1] = s2; }
    __syncthreads();
    float S = 0.f, Q = 0.f;
    #pragma unroll
    for (int i = 0; i < 16; i++) { S += red[i][0]; Q += red[i][1]; }
    float mean = S * (1.f/1024.f);
    float rstd = rsqrtf(Q * (1.f/1024.f) - mean*mean + 1e-5f);
    __syncthreads();
    return (v - mean) * rstd * g[c] + b[c];
}

// ---- k_post v5: 1 row/block, 1024 threads, dwordx4 weight loads, 16-way K-split ----
__global__ __launch_bounds__(1024) void k_post(
        const float* __restrict__ Upart, const float* __restrict__ dpart,
        const unsigned* __restrict__ WvP, const float* __restrict__ bv,
        const unsigned* __restrict__ WihP, const unsigned* __restrict__ WhhP,
        const float* __restrict__ bih, const float* __restrict__ bhh,
        const float* __restrict__ lnmg, const float* __restrict__ lnmb,
        const unsigned* __restrict__ W1P, const float* __restrict__ b1,
        const unsigned* __restrict__ W2P, const float* __restrict__ b2,
        const float* __restrict__ lnsg, const float* __restrict__ lnsb,
        const unsigned* __restrict__ WqP, const float* __restrict__ bq,
        const unsigned* __restrict__ WkTP, const float* __restrict__ bk,
        float* __restrict__ slots, unsigned short* __restrict__ qkg,
        float* __restrict__ qbkg, float* __restrict__ outp, int last) {
    __shared__ union {
        float PG[2][8][768];                              // 48KB: GRU partials
        struct { float P16[16][256]; float H2[8][512]; } s;  // 16+16KB
    } sm;
    __shared__ float A[256], B[256], G2[2][768], H[512];
    __shared__ float red[16][2];
    __shared__ float scal[1];
    int r = blockIdx.x, b = r >> 3, s = r & 7;
    int t = threadIdx.x, c = t & 255, q = t >> 8;
    int cg = t & 63, kg16 = t >> 6;   // 16 K-groups x 64 col-groups (x4 cols)
    // ---- P1: U partial reduce + denom + slots load
    {
        float u = 0.f;
        const float* ub = Upart + (long)b * NCHUNK * 2048 + s * 256 + c;
        #pragma unroll
        for (int i = 0; i < 8; i++) u += ub[(q * 8 + i) * 2048];
        sm.s.P16[q][c] = u;
        if (q == 1) B[c] = slots[r * 256 + c];
        if (t < 32) {
            float dv = dpart[(b * NCHUNK + t) * 8 + s];
            #pragma unroll
            for (int m = 16; m; m >>= 1) dv += __shfl_xor(dv, m);
            if (t == 0) scal[0] = dv;
        }
    }
    __syncthreads();
    float dn = 1.f / (scal[0] + (float)NPOS * EPS_F);
    if (q == 0) A[c] = sm.s.P16[0][c] + sm.s.P16[1][c] + sm.s.P16[2][c] + sm.s.P16[3][c];
    __syncthreads();
    // ---- Wv: 16 K-groups x 8 pairs, x4 columns
    {
        f32x4 acc = (f32x4)0.f;
        const uint4* wp = (const uint4*)(WvP + kg16 * 8 * 256 + 4 * cg);
        #pragma unroll
        for (int i = 0; i < 8; i++) {
            uint4 wv = wp[i * 64];
            fma4(acc, wv, A[2*(kg16*8+i)], A[2*(kg16*8+i)+1]);
        }
        *(f32x4*)&sm.s.P16[kg16][4*cg] = acc;
    }
    __syncthreads();
    float updtmp;
    {
        float ss = 0.f;
        #pragma unroll
        for (int k = 0; k < 16; k++) ss += sm.s.P16[k][c];
        updtmp = ss * dn + bv[c];
    }
    __syncthreads();
    if (q == 0) A[c] = updtmp;
    __syncthreads();
    // ---- GRU partials: h = ih/hh, 8 K-groups x 16 pairs, x4 cols, 3 submats
    {
        int h = t >> 9;             // 0: Wih(upd=A), 1: Whh(slots=B)
        int kg = (t >> 6) & 7;
        const float* src = h ? B : A;
        const unsigned* W = h ? WhhP : WihP;
        f32x4 ar = (f32x4)0.f, az = (f32x4)0.f, an = (f32x4)0.f;
        #pragma unroll 4
        for (int i = 0; i < 16; i++) {
            int hp = kg * 16 + i;
            float a0 = src[2*hp], a1 = src[2*hp+1];
            uint4 w0 = *(const uint4*)(W + hp*768 + 4*cg);
            uint4 w1 = *(const uint4*)(W + hp*768 + 256 + 4*cg);
            uint4 w2 = *(const uint4*)(W + hp*768 + 512 + 4*cg);
            fma4(ar, w0, a0, a1);
            fma4(az, w1, a0, a1);
            fma4(an, w2, a0, a1);
        }
        *(f32x4*)&sm.PG[h][kg][4*cg]       = ar;
        *(f32x4*)&sm.PG[h][kg][256 + 4*cg] = az;
        *(f32x4*)&sm.PG[h][kg][512 + 4*cg] = an;
    }
    __syncthreads();
    for (int idx = t; idx < 1536; idx += 1024) {
        int h = idx / 768, cc = idx - h * 768;
        float ss = 0.f;
        #pragma unroll
        for (int k = 0; k < 8; k++) ss += sm.PG[h][k][cc];
        G2[h][cc] = ss;
    }
    __syncthreads();
    // ---- GRU elementwise
    float spc = B[c];
    float gir = bih[c]     + G2[0][c];
    float giz = bih[c+256] + G2[0][c+256];
    float gin = bih[c+512] + G2[0][c+512];
    float ghr = bhh[c]     + G2[1][c];
    float ghz = bhh[c+256] + G2[1][c+256];
    float ghn = bhh[c+512] + G2[1][c+512];
    float rg = 1.f/(1.f + __expf(-(gir+ghr)));
    float zg = 1.f/(1.f + __expf(-(giz+ghz)));
    float ng = tanhf(gin + rg*ghn);
    float hnew = (1.f - zg)*ng + zg*spc;
    // ---- LN -> mm
    float mmc = ln1024(hnew, c, lnmg, lnmb, red);
    if (q == 0) A[c] = mmc;
    __syncthreads();
    // ---- MLP1: 8 K-groups x 16 pairs, 128 col-groups (N=512)
    {
        int kg = t >> 7, cg1 = t & 127;
        f32x4 acc = (f32x4)0.f;
        const uint4* wp = (const uint4*)(W1P + kg * 16 * 512 + 4 * cg1);
        #pragma unroll 4
        for (int i = 0; i < 16; i++) {
            uint4 wv = wp[i * 128];
            fma4(acc, wv, A[2*(kg*16+i)], A[2*(kg*16+i)+1]);
        }
        *(f32x4*)&sm.s.H2[kg][4*cg1] = acc;
    }
    __syncthreads();
    if (t < 512) {
        float ss = b1[t];
        #pragma unroll
        for (int k = 0; k < 8; k++) ss += sm.s.H2[k][t];
        H[t] = fmaxf(ss, 0.f);
    }
    __syncthreads();
    // ---- MLP2: 16 K-groups x 16 pairs (K=512), x4 cols
    {
        f32x4 acc = (f32x4)0.f;
        const uint4* wp = (const uint4*)(W2P + kg16 * 16 * 256 + 4 * cg);
        #pragma unroll 4
        for (int i = 0; i < 16; i++) {
            uint4 wv = wp[i * 64];
            fma4(acc, wv, H[2*(kg16*16+i)], H[2*(kg16*16+i)+1]);
        }
        *(f32x4*)&sm.s.P16[kg16][4*cg] = acc;
    }
    __syncthreads();
    float outc;
    {
        float ss = 0.f;
        #pragma unroll
        for (int k = 0; k < 16; k++) ss += sm.s.P16[k][c];
        outc = hnew + ss + b2[c];
    }
    if (t < 256) {
        slots[r*256 + c] = outc;
        if (last) outp[r*256 + c] = outc;
    }
    if (last) return;
    __syncthreads();
    // ---- LN(out) -> q -> qbk -> qk (next-iteration attention inputs)
    float sc = ln1024(outc, c, lnsg, lnsb, red);
    if (q == 0) A[c] = sc;
    __syncthreads();
    {
        f32x4 acc = (f32x4)0.f;
        const uint4* wp = (const uint4*)(WqP + kg16 * 8 * 256 + 4 * cg);
        #pragma unroll
        for (int i = 0; i < 8; i++) {
            uint4 wv = wp[i * 64];
            fma4(acc, wv, A[2*(kg16*8+i)], A[2*(kg16*8+i)+1]);
        }
        *(f32x4*)&sm.s.P16[kg16][4*cg] = acc;
    }
    __syncthreads();
    float qc;
    {
        float ss = 0.f;
        #pragma unroll
        for (int k = 0; k < 16; k++) ss += sm.s.P16[k][c];
        qc = ss + bq[c];
    }
    {   // qbk: block reduce of qc*bk[c] (each col appears 4x -> *0.25)
        float v = qc * bk[c];
        #pragma unroll
        for (int m = 32; m; m >>= 1) v += __shfl_xor(v, m);
        int w = t >> 6;
        if ((t & 63) == 0) red[w][0] = v;
        __syncthreads();
        if (t == 0) {
            float S = 0.f;
            #pragma unroll
            for (int i = 0; i < 16; i++) S += red[i][0];
            qbkg[r] = SCALE_F * 0.25f * S;
        }
        __syncthreads();
    }
    if (q == 0) A[c] = qc;
    __syncthreads();
    {
        f32x4 acc = (f32x4)0.f;
        const uint4* wp = (const uint4*)(WkTP + kg16 * 8 * 256 + 4 * cg);
        #pragma unroll
        for (int i = 0; i < 8; i++) {
            uint4 wv = wp[i * 64];
            fma4(acc, wv, A[2*(kg16*8+i)], A[2*(kg16*8+i)+1]);
        }
        *(f32x4*)&sm.s.P16[kg16][4*cg] = acc;
    }
    __syncthreads();
    if (t < 256) {
        float ss = 0.f;
        #pragma unroll
        for (int k = 0; k < 16; k++) ss += sm.s.P16[k][c];
        qkg[r*256 + c] = f2bf(SCALE_F * ss);
    }
}

extern "C" void kernel_launch(void* const* d_in, const int* in_sizes, int n_in,
                              void* d_out, int out_size, void* d_ws, size_t ws_size,
                              hipStream_t stream) {
    const float* inputs = (const float*)d_in[0];
    const float* noise  = (const float*)d_in[1];
    const float* mu     = (const float*)d_in[2];
    const float* sig    = (const float*)d_in[3];
    const float* lnig   = (const float*)d_in[4];
    const float* lnib   = (const float*)d_in[5];
    const float* lnsg   = (const float*)d_in[6];
    const float* lnsb   = (const float*)d_in[7];
    const float* lnmg   = (const float*)d_in[8];
    const float* lnmb   = (const float*)d_in[9];
    const float* Wq     = (const float*)d_in[10];
    const float* bq     = (const float*)d_in[11];
    const float* Wk     = (const float*)d_in[12];
    const float* bk     = (const float*)d_in[13];
    const float* Wv     = (const float*)d_in[14];
    const float* bv     = (const float*)d_in[15];
    const float* Wih    = (const float*)d_in[16];
    const float* Whh    = (const float*)d_in[17];
    const float* bih    = (const float*)d_in[18];
    const float* bhh    = (const float*)d_in[19];
    const float* W1     = (const float*)d_in[20];
    const float* b1     = (const float*)d_in[21];
    const float* W2     = (const float*)d_in[22];
    const float* b2     = (const float*)d_in[23];

    char* ws = (char*)d_ws;
    unsigned short* lnx = (unsigned short*)ws;
    size_t off = (size_t)NB * NPOS * HIDD * 2;                                   // 64 MB
    unsigned short* qkb = (unsigned short*)(ws + off); off += (size_t)NB*NSLOT*HIDD*2;
    float* qbk   = (float*)(ws + off); off += (size_t)NB*NSLOT*4;
    float* Upart = (float*)(ws + off); off += (size_t)NB*NCHUNK*NSLOT*HIDD*4;    // 8 MB
    float* dpart = (float*)(ws + off); off += (size_t)NB*NCHUNK*NSLOT*4;
    float* slots = (float*)(ws + off); off += (size_t)NB*NSLOT*DDIM*4;
    unsigned* WqP  = (unsigned*)(ws + off); off += 32768u*4;
    unsigned* WkTP = (unsigned*)(ws + off); off += 32768u*4;
    unsigned* WvP  = (unsigned*)(ws + off); off += 32768u*4;
    unsigned* WihP = (unsigned*)(ws + off); off += 98304u*4;
    unsigned* WhhP = (unsigned*)(ws + off); off += 98304u*4;
    unsigned* W1P  = (unsigned*)(ws + off); off += 65536u*4;
    unsigned* W2P  = (unsigned*)(ws + off); off += 65536u*4;

    k_prep<<<384, 256, 0, stream>>>(Wq, Wk, Wv, Wih, Whh, W1, W2,
                                    WqP, WkTP, WvP, WihP, WhhP, W1P, W2P);
    k_ln_in<<<NB*NPOS/4, 256, 0, stream>>>(inputs, lnig, lnib, lnx);
    k_init<<<NB*4, 256, 0, stream>>>(noise, mu, sig, lnsg, lnsb, Wq, bq, Wk, bk,
                                     slots, qkb, qbk);
    for (int it = 0; it < 3; it++) {
        k_stream<<<NB*NCHUNK, 128, 0, stream>>>(lnx, qkb, qbk, Upart, dpart);
        k_post<<<NB*NSLOT, 1024, 0, stream>>>(Upart, dpart,
                                              WvP, bv, WihP, WhhP, bih, bhh,
                                              lnmg, lnmb, W1P, b1, W2P, b2,
                                              lnsg, lnsb, WqP, bq, WkTP, bk,
                                              slots, qkb, qbk, (float*)d_out,
                                              it == 2 ? 1 : 0);
    }
}

// Round 7
// 232.979 us; speedup vs baseline: 5.6362x; 1.0157x over previous
//
#include <hip/hip_runtime.h>
#include <hip/hip_bf16.h>

#define NB 32
#define NPOS 4096
#define NSLOT 8
#define HIDD 256
#define DDIM 256
#define SCALE_F 0.0625f
#define EPS_F 1e-8f
#define NCHUNK 32     // chunks per batch (k_stream grid = NB*NCHUNK)
#define CPOS 128      // positions per chunk
#define TPOS 32       // positions per tile (2 waves x 16)

typedef __attribute__((ext_vector_type(4))) float f32x4;
typedef __attribute__((ext_vector_type(8))) short s16x8;
typedef __attribute__((ext_vector_type(2))) unsigned int u32x2;
typedef _Float16 h16x2 __attribute__((ext_vector_type(2)));

__device__ __forceinline__ unsigned short f2bf(float f) {
    unsigned int x = __float_as_uint(f);
    x = (x + 0x7fffu + ((x >> 16) & 1u)) >> 16;
    return (unsigned short)x;
}
__device__ __forceinline__ unsigned short f2h(float f) {
    _Float16 h = (_Float16)f;
    return __builtin_bit_cast(unsigned short, h);
}
__device__ __forceinline__ h16x2 u2h(unsigned u) { return __builtin_bit_cast(h16x2, u); }
__device__ __forceinline__ h16x2 mkh(float a0, float a1) {
    h16x2 r; r[0] = (_Float16)a0; r[1] = (_Float16)a1; return r;
}
// one x4 dot step: acc[j] += a0*lo(wv[j]) + a1*hi(wv[j]) via v_dot2_f32_f16
__device__ __forceinline__ void dot4(f32x4& acc, uint4 wv, h16x2 av) {
    acc[0] = __builtin_amdgcn_fdot2(av, u2h(wv.x), acc[0], false);
    acc[1] = __builtin_amdgcn_fdot2(av, u2h(wv.y), acc[1], false);
    acc[2] = __builtin_amdgcn_fdot2(av, u2h(wv.z), acc[2], false);
    acc[3] = __builtin_amdgcn_fdot2(av, u2h(wv.w), acc[3], false);
}

// ---------------- LayerNorm(inputs) -> bf16, one wave per row ----------------
__global__ __launch_bounds__(256) void k_ln_in(
        const float* __restrict__ x, const float* __restrict__ g,
        const float* __restrict__ b, unsigned short* __restrict__ lnx) {
    int lane = threadIdx.x & 63;
    int wave = threadIdx.x >> 6;
    long row = (long)blockIdx.x * 4 + wave;
    const float4* xr = (const float4*)(x + row * 256);
    float4 v = xr[lane];
    float s = v.x + v.y + v.z + v.w;
    float sq = v.x * v.x + v.y * v.y + v.z * v.z + v.w * v.w;
    #pragma unroll
    for (int m = 32; m; m >>= 1) { s += __shfl_xor(s, m); sq += __shfl_xor(sq, m); }
    float mean = s * 0.00390625f;
    float rstd = rsqrtf(sq * 0.00390625f - mean * mean + 1e-5f);
    const float4 gg = ((const float4*)g)[lane];
    const float4 bb = ((const float4*)b)[lane];
    ushort4 o;
    o.x = f2bf((v.x - mean) * rstd * gg.x + bb.x);
    o.y = f2bf((v.y - mean) * rstd * gg.y + bb.y);
    o.z = f2bf((v.z - mean) * rstd * gg.z + bb.z);
    o.w = f2bf((v.w - mean) * rstd * gg.w + bb.w);
    ((ushort4*)(lnx + row * 256))[lane] = o;
}

// ---------------- weight pack: f16 row-pair packed ----------------
__device__ __forceinline__ unsigned packrowh(const float* __restrict__ W, int hp, int N, int c) {
    return (unsigned)f2h(W[(2*hp)*N + c]) | ((unsigned)f2h(W[(2*hp+1)*N + c]) << 16);
}

__global__ __launch_bounds__(256) void k_prep(
        const float* __restrict__ Wq, const float* __restrict__ Wk,
        const float* __restrict__ Wv, const float* __restrict__ Wih,
        const float* __restrict__ Whh, const float* __restrict__ W1,
        const float* __restrict__ W2,
        unsigned* __restrict__ WqP, unsigned* __restrict__ WkTP,
        unsigned* __restrict__ WvP, unsigned* __restrict__ WihP,
        unsigned* __restrict__ WhhP, unsigned* __restrict__ W1P,
        unsigned* __restrict__ W2P) {
    int i = blockIdx.x * 256 + threadIdx.x;   // grid = 384 blocks -> i < 98304
    if (i < 32768) {
        int hp = i >> 8, c = i & 255;
        WqP[i] = packrowh(Wq, hp, 256, c);
        WvP[i] = packrowh(Wv, hp, 256, c);
        WkTP[i] = (unsigned)f2h(Wk[c*256 + 2*hp]) | ((unsigned)f2h(Wk[c*256 + 2*hp + 1]) << 16);
    }
    if (i < 65536) {
        int hp1 = i >> 9, c1 = i & 511;
        W1P[i] = packrowh(W1, hp1, 512, c1);
        int hp2 = i >> 8, c2 = i & 255;
        W2P[i] = packrowh(W2, hp2, 256, c2);
    }
    if (i < 98304) {
        int hp = i / 768, c = i % 768;
        WihP[i] = packrowh(Wih, hp, 768, c);
        WhhP[i] = packrowh(Whh, hp, 768, c);
    }
}

// ---- shared tail: LN(slot rows) -> q -> qbk, qk   (block = 2 rows, 256 thr) ----
__device__ __forceinline__ void qk_tail(
        float v0, float v1, int b, int s0,
        const float* __restrict__ lng, const float* __restrict__ lnb,
        const float* __restrict__ Wq, const float* __restrict__ bq,
        const float* __restrict__ Wk, const float* __restrict__ bk,
        unsigned short* __restrict__ qkg, float* __restrict__ qbkg,
        float (*sh)[256], float (*red)[4]) {
    int c = threadIdx.x;
    float s_0 = v0, q_0 = v0 * v0, s_1 = v1, q_1 = v1 * v1;
    #pragma unroll
    for (int m = 32; m; m >>= 1) {
        s_0 += __shfl_xor(s_0, m); q_0 += __shfl_xor(q_0, m);
        s_1 += __shfl_xor(s_1, m); q_1 += __shfl_xor(q_1, m);
    }
    if ((c & 63) == 0) { int w = c >> 6; red[w][0]=s_0; red[w][1]=q_0; red[w][2]=s_1; red[w][3]=q_1; }
    __syncthreads();
    float S0 = red[0][0]+red[1][0]+red[2][0]+red[3][0];
    float Q0 = red[0][1]+red[1][1]+red[2][1]+red[3][1];
    float S1 = red[0][2]+red[1][2]+red[2][2]+red[3][2];
    float Q1 = red[0][3]+red[1][3]+red[2][3]+red[3][3];
    float m0 = S0 * 0.00390625f, r0 = rsqrtf(Q0 * 0.00390625f - m0*m0 + 1e-5f);
    float m1 = S1 * 0.00390625f, r1 = rsqrtf(Q1 * 0.00390625f - m1*m1 + 1e-5f);
    float gc = lng[c], bc = lnb[c];
    sh[0][c] = (v0 - m0) * r0 * gc + bc;
    sh[1][c] = (v1 - m1) * r1 * gc + bc;
    __syncthreads();
    float qa0 = bq[c], qa1 = qa0;
    for (int h = 0; h < 256; h += 4) {
        float w0 = Wq[(h+0)*256+c], w1 = Wq[(h+1)*256+c];
        float w2 = Wq[(h+2)*256+c], w3 = Wq[(h+3)*256+c];
        float4 x0 = *(const float4*)&sh[0][h], x1 = *(const float4*)&sh[1][h];
        qa0 += x0.x*w0 + x0.y*w1 + x0.z*w2 + x0.w*w3;
        qa1 += x1.x*w0 + x1.y*w1 + x1.z*w2 + x1.w*w3;
    }
    __syncthreads();
    sh[0][c] = qa0; sh[1][c] = qa1;
    float bkc = bk[c];
    float p0 = qa0 * bkc, p1 = qa1 * bkc;
    #pragma unroll
    for (int m = 32; m; m >>= 1) { p0 += __shfl_xor(p0, m); p1 += __shfl_xor(p1, m); }
    __syncthreads();
    if ((c & 63) == 0) { int w = c >> 6; red[w][0] = p0; red[w][1] = p1; }
    __syncthreads();
    if (c < 2) qbkg[b*8 + s0 + c] = SCALE_F * (red[0][c]+red[1][c]+red[2][c]+red[3][c]);
    float k0 = 0.f, k1 = 0.f;
    const float* wkr = Wk + (long)c * 256;
    for (int d = 0; d < 256; d += 4) {
        float4 wk4 = *(const float4*)&wkr[d];
        float4 x0 = *(const float4*)&sh[0][d], x1 = *(const float4*)&sh[1][d];
        k0 += x0.x*wk4.x + x0.y*wk4.y + x0.z*wk4.z + x0.w*wk4.w;
        k1 += x1.x*wk4.x + x1.y*wk4.y + x1.z*wk4.z + x1.w*wk4.w;
    }
    qkg[(b*8 + s0    )*256 + c] = f2bf(SCALE_F * k0);
    qkg[(b*8 + s0 + 1)*256 + c] = f2bf(SCALE_F * k1);
}

// ---------------- iter-0: slots init + LN + q + qk ----------------
__global__ __launch_bounds__(256) void k_init(
        const float* __restrict__ noise, const float* __restrict__ mu,
        const float* __restrict__ sig, const float* __restrict__ lng,
        const float* __restrict__ lnb, const float* __restrict__ Wq,
        const float* __restrict__ bq, const float* __restrict__ Wk,
        const float* __restrict__ bk, float* __restrict__ slots,
        unsigned short* __restrict__ qkg, float* __restrict__ qbkg) {
    __shared__ float sh[2][256];
    __shared__ float red[4][4];
    int b = blockIdx.x >> 2, rp = blockIdx.x & 3;
    int s0 = rp * 2, r0 = b * 8 + s0;
    int c = threadIdx.x;
    float v0 = mu[c] + sig[c] * noise[r0*256 + c];
    float v1 = mu[c] + sig[c] * noise[(r0+1)*256 + c];
    slots[r0*256 + c] = v0;
    slots[(r0+1)*256 + c] = v1;
    qk_tail(v0, v1, b, s0, lng, lnb, Wq, bq, Wk, bk, qkg, qbkg, sh, red);
}

// ------- streaming attention: MFMA dots -> softmax(slot) -> MFMA updates -------
// grid = NB * NCHUNK blocks, 128 threads (2 waves), 4 tiles of 32 positions
__global__ __launch_bounds__(128) void k_stream(
        const unsigned short* __restrict__ lnx, const unsigned short* __restrict__ qk,
        const float* __restrict__ qbk, float* __restrict__ Upart,
        float* __restrict__ dpart) {
    __shared__ unsigned short xt[TPOS * 256];   // chunk-XOR swizzled
    __shared__ float Ured[8 * 256];
    __shared__ float dred[8];
    int b = blockIdx.x >> 5, ch = blockIdx.x & 31;
    int t = threadIdx.x;
    int l = t & 63, w = t >> 6;
    for (int i = t; i < 2048; i += 128) Ured[i] = 0.f;
    if (t < 8) dred[t] = 0.f;
    int slot = l & 15, g = l >> 4;
    s16x8 qkf[8];
    float qbkv = 0.f;
    if (slot < 8) {
        const unsigned short* qrow = qk + (b*8 + slot) * 256;
        #pragma unroll
        for (int hk = 0; hk < 8; hk++)
            qkf[hk] = *(const s16x8*)(qrow + hk*32 + 8*g);
        qbkv = qbk[b*8 + slot];
    } else {
        #pragma unroll
        for (int hk = 0; hk < 8; hk++) qkf[hk] = (s16x8)0;
    }
    f32x4 uacc[16];
    #pragma unroll
    for (int i = 0; i < 16; i++) uacc[i] = (f32x4)0.f;
    float dreg = 0.f;
    int gbase = (b * NPOS + ch * CPOS) * 256;
    int pw = w * 16;
    __syncthreads();
    for (int tile = 0; tile < 4; tile++) {
        #pragma unroll
        for (int i = 0; i < 8; i++) {
            int c = t + 128 * i;
            int p = c >> 5, hc = c & 31;
            int4 v = *(const int4*)(lnx + gbase + (tile*TPOS + p)*256 + hc*8);
            *(int4*)&xt[p*256 + ((hc ^ (p & 15)) << 3)] = v;
        }
        __syncthreads();
        f32x4 acc = (f32x4)0.f;
        {
            int prow = pw + (l & 15);
            const unsigned short* xrow = &xt[prow * 256];
            int sw = prow & 15;
            #pragma unroll
            for (int hk = 0; hk < 8; hk++) {
                s16x8 a = *(const s16x8*)(xrow + (((hk*4 + g) ^ sw) << 3));
                acc = __builtin_amdgcn_mfma_f32_16x16x32_bf16(a, qkf[hk], acc, 0, 0, 0);
            }
        }
        float at[4];
        #pragma unroll
        for (int r = 0; r < 4; r++) {
            float v = acc[r] + qbkv;
            float m = v;
            m = fmaxf(m, __shfl_xor(m, 1));
            m = fmaxf(m, __shfl_xor(m, 2));
            m = fmaxf(m, __shfl_xor(m, 4));
            float e = __expf(v - m);
            float sum = e;
            sum += __shfl_xor(sum, 1);
            sum += __shfl_xor(sum, 2);
            sum += __shfl_xor(sum, 4);
            float a = e / sum;
            at[r] = a;
            dreg += a;
        }
        u32x2 a2;
        a2.x = (unsigned)f2bf(at[0]) | ((unsigned)f2bf(at[1]) << 16);
        a2.y = (unsigned)f2bf(at[2]) | ((unsigned)f2bf(at[3]) << 16);
        int p0 = pw + 4 * g;
        int hl = l & 7;
        #pragma unroll
        for (int hc = 0; hc < 16; hc++) {
            int hcol = hc * 2 + ((l & 15) >> 3);
            unsigned e0 = xt[(p0+0)*256 + ((hcol ^ ((p0+0) & 15)) << 3) + hl];
            unsigned e1 = xt[(p0+1)*256 + ((hcol ^ ((p0+1) & 15)) << 3) + hl];
            unsigned e2 = xt[(p0+2)*256 + ((hcol ^ ((p0+2) & 15)) << 3) + hl];
            unsigned e3 = xt[(p0+3)*256 + ((hcol ^ ((p0+3) & 15)) << 3) + hl];
            u32x2 b2;
            b2.x = e0 | (e1 << 16);
            b2.y = e2 | (e3 << 16);
            asm volatile("v_mfma_f32_16x16x16_bf16 %0, %1, %2, %0"
                         : "+v"(uacc[hc]) : "v"(a2), "v"(b2));
        }
        __syncthreads();
    }
    if (g < 2) {
        #pragma unroll
        for (int hc = 0; hc < 16; hc++) {
            int h = hc * 16 + (l & 15);
            #pragma unroll
            for (int r = 0; r < 4; r++)
                atomicAdd(&Ured[(4*g + r)*256 + h], uacc[hc][r]);
        }
    }
    dreg += __shfl_xor(dreg, 16);
    dreg += __shfl_xor(dreg, 32);
    if (slot < 8 && g == 0) atomicAdd(&dred[slot], dreg);
    __syncthreads();
    float* up = Upart + (long)(b * NCHUNK + ch) * 2048;
    for (int i = t; i < 2048; i += 128) up[i] = Ured[i];
    if (t < 8) dpart[(b * NCHUNK + ch) * 8 + t] = dred[t];
}

// ---- 1024-thread duplicated-column layernorm (each value appears 4x) ----
__device__ __forceinline__ float ln1024(float v, int c, const float* __restrict__ g,
                                        const float* __restrict__ b, float (*red)[2]) {
    float s1 = v, s2 = v * v;
    #pragma unroll
    for (int m = 32; m; m >>= 1) { s1 += __shfl_xor(s1, m); s2 += __shfl_xor(s2, m); }
    int w = threadIdx.x >> 6;
    if ((threadIdx.x & 63) == 0) { red[w][0] = s1; red[w][1] = s2; }
    __syncthreads();
    float S = 0.f, Q = 0.f;
    #pragma unroll
    for (int i = 0; i < 16; i++) { S += red[i][0]; Q += red[i][1]; }
    float mean = S * (1.f/1024.f);
    float rstd = rsqrtf(Q * (1.f/1024.f) - mean*mean + 1e-5f);
    __syncthreads();
    return (v - mean) * rstd * g[c] + b[c];
}

// ---- k_post v6: 1 row/block, 1024 threads, f16 weights + v_dot2_f32_f16 ----
__global__ __launch_bounds__(1024) void k_post(
        const float* __restrict__ Upart, const float* __restrict__ dpart,
        const unsigned* __restrict__ WvP, const float* __restrict__ bv,
        const unsigned* __restrict__ WihP, const unsigned* __restrict__ WhhP,
        const float* __restrict__ bih, const float* __restrict__ bhh,
        const float* __restrict__ lnmg, const float* __restrict__ lnmb,
        const unsigned* __restrict__ W1P, const float* __restrict__ b1,
        const unsigned* __restrict__ W2P, const float* __restrict__ b2,
        const float* __restrict__ lnsg, const float* __restrict__ lnsb,
        const unsigned* __restrict__ WqP, const float* __restrict__ bq,
        const unsigned* __restrict__ WkTP, const float* __restrict__ bk,
        float* __restrict__ slots, unsigned short* __restrict__ qkg,
        float* __restrict__ qbkg, float* __restrict__ outp, int last) {
    __shared__ union {
        float PG[2][8][768];                              // 48KB: GRU partials
        struct { float P16[16][256]; float H2[8][512]; } s;  // 16+16KB
    } sm;
    __shared__ float A[256], B[256], G2[2][768], H[512];
    __shared__ float red[16][2];
    __shared__ float scal[1];
    int r = blockIdx.x, b = r >> 3, s = r & 7;
    int t = threadIdx.x, c = t & 255, q = t >> 8;
    int cg = t & 63, kg16 = t >> 6;   // 16 K-groups x 64 col-groups (x4 cols)
    // ---- P1: U partial reduce + denom + slots load
    {
        float u = 0.f;
        const float* ub = Upart + (long)b * NCHUNK * 2048 + s * 256 + c;
        #pragma unroll
        for (int i = 0; i < 8; i++) u += ub[(q * 8 + i) * 2048];
        sm.s.P16[q][c] = u;
        if (q == 1) B[c] = slots[r * 256 + c];
        if (t < 32) {
            float dv = dpart[(b * NCHUNK + t) * 8 + s];
            #pragma unroll
            for (int m = 16; m; m >>= 1) dv += __shfl_xor(dv, m);
            if (t == 0) scal[0] = dv;
        }
    }
    __syncthreads();
    float dn = 1.f / (scal[0] + (float)NPOS * EPS_F);
    if (q == 0) A[c] = sm.s.P16[0][c] + sm.s.P16[1][c] + sm.s.P16[2][c] + sm.s.P16[3][c];
    __syncthreads();
    // ---- Wv: 16 K-groups x 8 pairs, x4 columns
    {
        f32x4 acc = (f32x4)0.f;
        const uint4* wp = (const uint4*)(WvP + kg16 * 8 * 256 + 4 * cg);
        #pragma unroll
        for (int i = 0; i < 8; i++) {
            uint4 wv = wp[i * 64];
            dot4(acc, wv, mkh(A[2*(kg16*8+i)], A[2*(kg16*8+i)+1]));
        }
        *(f32x4*)&sm.s.P16[kg16][4*cg] = acc;
    }
    __syncthreads();
    float updtmp;
    {
        float ss = 0.f;
        #pragma unroll
        for (int k = 0; k < 16; k++) ss += sm.s.P16[k][c];
        updtmp = ss * dn + bv[c];
    }
    __syncthreads();
    if (q == 0) A[c] = updtmp;
    __syncthreads();
    // ---- GRU partials: h = ih/hh, 8 K-groups x 16 pairs, x4 cols, 3 submats
    {
        int h = t >> 9;             // 0: Wih(upd=A), 1: Whh(slots=B)
        int kg = (t >> 6) & 7;
        const float* src = h ? B : A;
        const unsigned* W = h ? WhhP : WihP;
        f32x4 ar = (f32x4)0.f, az = (f32x4)0.f, an = (f32x4)0.f;
        #pragma unroll 4
        for (int i = 0; i < 16; i++) {
            int hp = kg * 16 + i;
            h16x2 av = mkh(src[2*hp], src[2*hp+1]);
            uint4 w0 = *(const uint4*)(W + hp*768 + 4*cg);
            uint4 w1 = *(const uint4*)(W + hp*768 + 256 + 4*cg);
            uint4 w2 = *(const uint4*)(W + hp*768 + 512 + 4*cg);
            dot4(ar, w0, av);
            dot4(az, w1, av);
            dot4(an, w2, av);
        }
        *(f32x4*)&sm.PG[h][kg][4*cg]       = ar;
        *(f32x4*)&sm.PG[h][kg][256 + 4*cg] = az;
        *(f32x4*)&sm.PG[h][kg][512 + 4*cg] = an;
    }
    __syncthreads();
    for (int idx = t; idx < 1536; idx += 1024) {
        int h = idx / 768, cc = idx - h * 768;
        float ss = 0.f;
        #pragma unroll
        for (int k = 0; k < 8; k++) ss += sm.PG[h][k][cc];
        G2[h][cc] = ss;
    }
    __syncthreads();
    // ---- GRU elementwise
    float spc = B[c];
    float gir = bih[c]     + G2[0][c];
    float giz = bih[c+256] + G2[0][c+256];
    float gin = bih[c+512] + G2[0][c+512];
    float ghr = bhh[c]     + G2[1][c];
    float ghz = bhh[c+256] + G2[1][c+256];
    float ghn = bhh[c+512] + G2[1][c+512];
    float rg = 1.f/(1.f + __expf(-(gir+ghr)));
    float zg = 1.f/(1.f + __expf(-(giz+ghz)));
    float ng = tanhf(gin + rg*ghn);
    float hnew = (1.f - zg)*ng + zg*spc;
    // ---- LN -> mm
    float mmc = ln1024(hnew, c, lnmg, lnmb, red);
    if (q == 0) A[c] = mmc;
    __syncthreads();
    // ---- MLP1: 8 K-groups x 16 pairs, 128 col-groups (N=512)
    {
        int kg = t >> 7, cg1 = t & 127;
        f32x4 acc = (f32x4)0.f;
        const uint4* wp = (const uint4*)(W1P + kg * 16 * 512 + 4 * cg1);
        #pragma unroll 4
        for (int i = 0; i < 16; i++) {
            uint4 wv = wp[i * 128];
            dot4(acc, wv, mkh(A[2*(kg*16+i)], A[2*(kg*16+i)+1]));
        }
        *(f32x4*)&sm.s.H2[kg][4*cg1] = acc;
    }
    __syncthreads();
    if (t < 512) {
        float ss = b1[t];
        #pragma unroll
        for (int k = 0; k < 8; k++) ss += sm.s.H2[k][t];
        H[t] = fmaxf(ss, 0.f);
    }
    __syncthreads();
    // ---- MLP2: 16 K-groups x 16 pairs (K=512), x4 cols
    {
        f32x4 acc = (f32x4)0.f;
        const uint4* wp = (const uint4*)(W2P + kg16 * 16 * 256 + 4 * cg);
        #pragma unroll 4
        for (int i = 0; i < 16; i++) {
            uint4 wv = wp[i * 64];
            dot4(acc, wv, mkh(H[2*(kg16*16+i)], H[2*(kg16*16+i)+1]));
        }
        *(f32x4*)&sm.s.P16[kg16][4*cg] = acc;
    }
    __syncthreads();
    float outc;
    {
        float ss = 0.f;
        #pragma unroll
        for (int k = 0; k < 16; k++) ss += sm.s.P16[k][c];
        outc = hnew + ss + b2[c];
    }
    if (t < 256) {
        slots[r*256 + c] = outc;
        if (last) outp[r*256 + c] = outc;
    }
    if (last) return;
    __syncthreads();
    // ---- LN(out) -> q -> qbk -> qk (next-iteration attention inputs)
    float sc = ln1024(outc, c, lnsg, lnsb, red);
    if (q == 0) A[c] = sc;
    __syncthreads();
    {
        f32x4 acc = (f32x4)0.f;
        const uint4* wp = (const uint4*)(WqP + kg16 * 8 * 256 + 4 * cg);
        #pragma unroll
        for (int i = 0; i < 8; i++) {
            uint4 wv = wp[i * 64];
            dot4(acc, wv, mkh(A[2*(kg16*8+i)], A[2*(kg16*8+i)+1]));
        }
        *(f32x4*)&sm.s.P16[kg16][4*cg] = acc;
    }
    __syncthreads();
    float qc;
    {
        float ss = 0.f;
        #pragma unroll
        for (int k = 0; k < 16; k++) ss += sm.s.P16[k][c];
        qc = ss + bq[c];
    }
    {   // qbk: block reduce of qc*bk[c] (each col appears 4x -> *0.25)
        float v = qc * bk[c];
        #pragma unroll
        for (int m = 32; m; m >>= 1) v += __shfl_xor(v, m);
        int w = t >> 6;
        if ((t & 63) == 0) red[w][0] = v;
        __syncthreads();
        if (t == 0) {
            float S = 0.f;
            #pragma unroll
            for (int i = 0; i < 16; i++) S += red[i][0];
            qbkg[r] = SCALE_F * 0.25f * S;
        }
        __syncthreads();
    }
    if (q == 0) A[c] = qc;
    __syncthreads();
    {
        f32x4 acc = (f32x4)0.f;
        const uint4* wp = (const uint4*)(WkTP + kg16 * 8 * 256 + 4 * cg);
        #pragma unroll
        for (int i = 0; i < 8; i++) {
            uint4 wv = wp[i * 64];
            dot4(acc, wv, mkh(A[2*(kg16*8+i)], A[2*(kg16*8+i)+1]));
        }
        *(f32x4*)&sm.s.P16[kg16][4*cg] = acc;
    }
    __syncthreads();
    if (t < 256) {
        float ss = 0.f;
        #pragma unroll
        for (int k = 0; k < 16; k++) ss += sm.s.P16[k][c];
        qkg[r*256 + c] = f2bf(SCALE_F * ss);
    }
}

extern "C" void kernel_launch(void* const* d_in, const int* in_sizes, int n_in,
                              void* d_out, int out_size, void* d_ws, size_t ws_size,
                              hipStream_t stream) {
    const float* inputs = (const float*)d_in[0];
    const float* noise  = (const float*)d_in[1];
    const float* mu     = (const float*)d_in[2];
    const float* sig    = (const float*)d_in[3];
    const float* lnig   = (const float*)d_in[4];
    const float* lnib   = (const float*)d_in[5];
    const float* lnsg   = (const float*)d_in[6];
    const float* lnsb   = (const float*)d_in[7];
    const float* lnmg   = (const float*)d_in[8];
    const float* lnmb   = (const float*)d_in[9];
    const float* Wq     = (const float*)d_in[10];
    const float* bq     = (const float*)d_in[11];
    const float* Wk     = (const float*)d_in[12];
    const float* bk     = (const float*)d_in[13];
    const float* Wv     = (const float*)d_in[14];
    const float* bv     = (const float*)d_in[15];
    const float* Wih    = (const float*)d_in[16];
    const float* Whh    = (const float*)d_in[17];
    const float* bih    = (const float*)d_in[18];
    const float* bhh    = (const float*)d_in[19];
    const float* W1     = (const float*)d_in[20];
    const float* b1     = (const float*)d_in[21];
    const float* W2     = (const float*)d_in[22];
    const float* b2     = (const float*)d_in[23];

    char* ws = (char*)d_ws;
    unsigned short* lnx = (unsigned short*)ws;
    size_t off = (size_t)NB * NPOS * HIDD * 2;                                   // 64 MB
    unsigned short* qkb = (unsigned short*)(ws + off); off += (size_t)NB*NSLOT*HIDD*2;
    float* qbk   = (float*)(ws + off); off += (size_t)NB*NSLOT*4;
    float* Upart = (float*)(ws + off); off += (size_t)NB*NCHUNK*NSLOT*HIDD*4;    // 8 MB
    float* dpart = (float*)(ws + off); off += (size_t)NB*NCHUNK*NSLOT*4;
    float* slots = (float*)(ws + off); off += (size_t)NB*NSLOT*DDIM*4;
    unsigned* WqP  = (unsigned*)(ws + off); off += 32768u*4;
    unsigned* WkTP = (unsigned*)(ws + off); off += 32768u*4;
    unsigned* WvP  = (unsigned*)(ws + off); off += 32768u*4;
    unsigned* WihP = (unsigned*)(ws + off); off += 98304u*4;
    unsigned* WhhP = (unsigned*)(ws + off); off += 98304u*4;
    unsigned* W1P  = (unsigned*)(ws + off); off += 65536u*4;
    unsigned* W2P  = (unsigned*)(ws + off); off += 65536u*4;

    k_prep<<<384, 256, 0, stream>>>(Wq, Wk, Wv, Wih, Whh, W1, W2,
                                    WqP, WkTP, WvP, WihP, WhhP, W1P, W2P);
    k_ln_in<<<NB*NPOS/4, 256, 0, stream>>>(inputs, lnig, lnib, lnx);
    k_init<<<NB*4, 256, 0, stream>>>(noise, mu, sig, lnsg, lnsb, Wq, bq, Wk, bk,
                                     slots, qkb, qbk);
    for (int it = 0; it < 3; it++) {
        k_stream<<<NB*NCHUNK, 128, 0, stream>>>(lnx, qkb, qbk, Upart, dpart);
        k_post<<<NB*NSLOT, 1024, 0, stream>>>(Upart, dpart,
                                              WvP, bv, WihP, WhhP, bih, bhh,
                                              lnmg, lnmb, W1P, b1, W2P, b2,
                                              lnsg, lnsb, WqP, bq, WkTP, bk,
                                              slots, qkb, qbk, (float*)d_out,
                                              it == 2 ? 1 : 0);
    }
}